// Round 13
// baseline (672.162 us; speedup 1.0000x reference)
//
#include <hip/hip_runtime.h>
#include <hip/hip_bf16.h>
#include <cmath>

typedef __bf16 bf16_t;
typedef __bf16 bf16x8 __attribute__((ext_vector_type(8)));
typedef float f32x4 __attribute__((ext_vector_type(4)));

#define DEV __device__ __forceinline__

static constexpr int BB = 2, SS = 2048, DD = 2048, HH = 16, HDIM = 128, II = 5504;
static constexpr int MM = BB * SS; // 4096

DEV void gload_lds16(const void* g, void* l) {
    __builtin_amdgcn_global_load_lds(
        (__attribute__((address_space(1))) void*)const_cast<void*>(g),
        (__attribute__((address_space(3))) void*)l, 16, 0, 0);
}

// ---------------- RMSNorm: f32 in -> bf16 out ----------------
__global__ __launch_bounds__(256) void rmsnorm_k(const float* __restrict__ x,
                                                 const float* __restrict__ w,
                                                 bf16_t* __restrict__ out) {
    int row = blockIdx.x;
    int t = threadIdx.x;
    const float4* xr = (const float4*)(x + (size_t)row * DD);
    float4 a = xr[t];
    float4 b = xr[t + 256];
    float ss = a.x * a.x + a.y * a.y + a.z * a.z + a.w * a.w +
               b.x * b.x + b.y * b.y + b.z * b.z + b.w * b.w;
    for (int m = 1; m < 64; m <<= 1) ss += __shfl_xor(ss, m);
    __shared__ float red[4];
    int lane = t & 63, wv = t >> 6;
    if (lane == 0) red[wv] = ss;
    __syncthreads();
    float scale = rsqrtf((red[0] + red[1] + red[2] + red[3]) * (1.0f / DD) + 1e-6f);
    const float4* w4 = (const float4*)w;
    float4 wa = w4[t], wb = w4[t + 256];
    bf16_t* o = out + (size_t)row * DD;
    union { bf16_t h[4]; ushort4 u; } pa, pb;
    pa.h[0] = (bf16_t)(a.x * scale * wa.x); pa.h[1] = (bf16_t)(a.y * scale * wa.y);
    pa.h[2] = (bf16_t)(a.z * scale * wa.z); pa.h[3] = (bf16_t)(a.w * scale * wa.w);
    pb.h[0] = (bf16_t)(b.x * scale * wb.x); pb.h[1] = (bf16_t)(b.y * scale * wb.y);
    pb.h[2] = (bf16_t)(b.z * scale * wb.z); pb.h[3] = (bf16_t)(b.w * scale * wb.w);
    ((ushort4*)o)[t] = pa.u;
    ((ushort4*)o)[t + 256] = pb.u;
}

// ---------------- RoPE tables ----------------
__global__ void rope_tables_k(float* __restrict__ cosb, float* __restrict__ sinb) {
    int s = blockIdx.x;
    int d = threadIdx.x;       // 0..127
    int j = d & 63;
    float inv = powf(10000.0f, -(2.0f * (float)j) / 128.0f);
    float ang = (float)s * inv;
    cosb[s * HDIM + d] = cosf(ang);
    sinb[s * HDIM + d] = sinf(ang);
}

// ---------------- RoPE apply (in-place on q and k, bf16) ----------------
__global__ __launch_bounds__(256) void rope_apply_k(bf16_t* __restrict__ q,
                                                    bf16_t* __restrict__ k,
                                                    const float* __restrict__ cosb,
                                                    const float* __restrict__ sinb) {
    int t = blockIdx.x * 256 + threadIdx.x;   // [0, M*H*64)
    int j = t & 63;
    int h = (t >> 6) & 15;
    int m = t >> 10;          // 0..4095
    int s = m & (SS - 1);
    size_t idx = (size_t)m * DD + h * HDIM + j;
    float c = cosb[s * HDIM + j];
    float sn = sinb[s * HDIM + j];
    float q1 = (float)q[idx], q2 = (float)q[idx + 64];
    q[idx]      = (bf16_t)(q1 * c - q2 * sn);
    q[idx + 64] = (bf16_t)(q2 * c + q1 * sn);
    float k1 = (float)k[idx], k2 = (float)k[idx + 64];
    k[idx]      = (bf16_t)(k1 * c - k2 * sn);
    k[idx + 64] = (bf16_t)(k2 * c + k1 * sn);
}

// ---------------- convert + transpose: W[K][N] f32 -> Wt[N][K] bf16 ----------------
__global__ __launch_bounds__(256) void convT_k(const float* __restrict__ W,
                                               bf16_t* __restrict__ Wt,
                                               int K, int N) {
    __shared__ float tile[32][33];
    int n0 = blockIdx.x * 32, k0 = blockIdx.y * 32;
    int tx = threadIdx.x & 31, ty = threadIdx.x >> 5;  // ty 0..7
    for (int i = 0; i < 4; ++i)
        tile[ty + 8 * i][tx] = W[(size_t)(k0 + ty + 8 * i) * N + n0 + tx];
    __syncthreads();
    for (int i = 0; i < 4; ++i)
        Wt[(size_t)(n0 + ty + 8 * i) * K + k0 + tx] = (bf16_t)tile[tx][ty + 8 * i];
}

// ---------------- V transpose: vb[b][s][hd] bf16 -> vtb[b][hd][s] bf16 ----------------
__global__ __launch_bounds__(256) void vtrans_k(const bf16_t* __restrict__ vbp,
                                                bf16_t* __restrict__ vtb) {
    __shared__ ushort tile[32][33];
    int b = blockIdx.z;
    int s0 = blockIdx.y * 32, c0 = blockIdx.x * 32;
    int tx = threadIdx.x & 31, ty = threadIdx.x >> 5;  // ty 0..7
    const ushort* in = (const ushort*)vbp + (size_t)b * SS * DD;
    ushort* out = (ushort*)vtb + (size_t)b * DD * SS;
    for (int i = 0; i < 4; ++i)
        tile[ty + 8 * i][tx] = in[(size_t)(s0 + ty + 8 * i) * DD + c0 + tx];
    __syncthreads();
    for (int i = 0; i < 4; ++i)
        out[(size_t)(c0 + ty + 8 * i) * SS + s0 + tx] = tile[tx][ty + 8 * i];
}

// ---------------- GEMM (r5-proven): C[M][N] = A[M][K] * Bt[N][K]^T ----------------
// EPI 0: bf16 store. EPI 1: f32 store = res + acc.
template <int EPI>
__global__ __launch_bounds__(256, 2) void gemm_bt(const bf16_t* __restrict__ A,
                                                  const bf16_t* __restrict__ Bt,
                                                  void* __restrict__ outp,
                                                  const float* __restrict__ res,
                                                  int M, int N, int K) {
    __shared__ __align__(16) bf16_t ldsA[128 * 64];
    __shared__ __align__(16) bf16_t ldsB[128 * 64];
    int tid = threadIdx.x, lane = tid & 63, w = tid >> 6;
    int lr = lane & 15, lg = lane >> 4;

    int GX = gridDim.x, GYd = gridDim.y;
    int bid = blockIdx.y * GX + blockIdx.x;
    int nwg = GX * GYd;
    int qc = nwg >> 3, rc = nwg & 7;
    int xcd = bid & 7, jj = bid >> 3;
    int wg = (xcd < rc ? xcd * (qc + 1) : rc * (qc + 1) + (xcd - rc) * qc) + jj;
    int bx = wg / GYd;
    int by = wg % GYd;

    int m0 = by * 128, n0 = bx * 128;
    int wr = w >> 1, wc = w & 1;
    f32x4 acc[4][4] = {};
    int srow = w * 8 + (lane >> 3);  // 0..31
    int sslot = lane & 7;

    for (int kt = 0; kt < K; kt += 64) {
        for (int i = 0; i < 4; ++i) {
            int row = i * 32 + srow;
            int sp = sslot ^ (row & 7);
            gload_lds16(A + (size_t)(m0 + row) * K + kt + sp * 8,
                        ldsA + i * 2048 + w * 512);
            gload_lds16(Bt + (size_t)(n0 + row) * K + kt + sp * 8,
                        ldsB + i * 2048 + w * 512);
        }
        asm volatile("s_waitcnt vmcnt(0)" ::: "memory");
        __syncthreads();
        for (int kk = 0; kk < 2; ++kk) {
            bf16x8 af[4], bfm[4];
            for (int x = 0; x < 4; ++x) {
                int ra = wr * 64 + x * 16 + lr;
                int sa = (kk * 4 + lg) ^ (ra & 7);
                af[x] = *(const bf16x8*)(ldsA + ra * 64 + sa * 8);
                int rb = wc * 64 + x * 16 + lr;
                int sb = (kk * 4 + lg) ^ (rb & 7);
                bfm[x] = *(const bf16x8*)(ldsB + rb * 64 + sb * 8);
            }
            for (int mi = 0; mi < 4; ++mi)
                for (int ni = 0; ni < 4; ++ni)
                    acc[mi][ni] = __builtin_amdgcn_mfma_f32_16x16x32_bf16(
                        af[mi], bfm[ni], acc[mi][ni], 0, 0, 0);
        }
        __syncthreads();
    }

    for (int mi = 0; mi < 4; ++mi) {
        int mbase = m0 + wr * 64 + mi * 16 + lg * 4;
        for (int ni = 0; ni < 4; ++ni) {
            int n = n0 + wc * 64 + ni * 16 + lr;
            f32x4 v = acc[mi][ni];
            for (int r = 0; r < 4; ++r) {
                size_t idx = (size_t)(mbase + r) * N + n;
                if (EPI == 0) ((bf16_t*)outp)[idx] = (bf16_t)v[r];
                else          ((float*)outp)[idx] = res[idx] + v[r];
            }
        }
    }
}

// ---------------- Triple-B GEMM: one A-tile, three B-panels (Q,K,V) ----------------
// Extension of proven gemm_dual: 4 waves, 64x64 quadrants, 4x16KB LDS, 512 blocks @ 2/CU.
__global__ __launch_bounds__(256, 2) void gemm_tri(const bf16_t* __restrict__ A,
                                                   const bf16_t* __restrict__ B1,
                                                   const bf16_t* __restrict__ B2,
                                                   const bf16_t* __restrict__ B3,
                                                   bf16_t* __restrict__ out1,
                                                   bf16_t* __restrict__ out2,
                                                   bf16_t* __restrict__ out3,
                                                   int M, int N, int K) {
    __shared__ __align__(16) bf16_t ldsA[128 * 64];
    __shared__ __align__(16) bf16_t ldsB1[128 * 64];
    __shared__ __align__(16) bf16_t ldsB2[128 * 64];
    __shared__ __align__(16) bf16_t ldsB3[128 * 64];
    int tid = threadIdx.x, lane = tid & 63, w = tid >> 6;
    int lr = lane & 15, lg = lane >> 4;

    int GX = gridDim.x, GYd = gridDim.y;
    int bid = blockIdx.y * GX + blockIdx.x;
    int nwg = GX * GYd;
    int qc = nwg >> 3, rc = nwg & 7;
    int xcd = bid & 7, jj = bid >> 3;
    int wg = (xcd < rc ? xcd * (qc + 1) : rc * (qc + 1) + (xcd - rc) * qc) + jj;
    int bx = wg / GYd;
    int by = wg % GYd;

    int m0 = by * 128, n0 = bx * 128;
    int wr = w >> 1, wc = w & 1;
    f32x4 acc1[4][4] = {};
    f32x4 acc2[4][4] = {};
    f32x4 acc3[4][4] = {};
    int srow = w * 8 + (lane >> 3);  // 0..31
    int sslot = lane & 7;

    for (int kt = 0; kt < K; kt += 64) {
        for (int i = 0; i < 4; ++i) {
            int row = i * 32 + srow;
            int sp = sslot ^ (row & 7);
            gload_lds16(A  + (size_t)(m0 + row) * K + kt + sp * 8, ldsA  + i * 2048 + w * 512);
            gload_lds16(B1 + (size_t)(n0 + row) * K + kt + sp * 8, ldsB1 + i * 2048 + w * 512);
            gload_lds16(B2 + (size_t)(n0 + row) * K + kt + sp * 8, ldsB2 + i * 2048 + w * 512);
            gload_lds16(B3 + (size_t)(n0 + row) * K + kt + sp * 8, ldsB3 + i * 2048 + w * 512);
        }
        asm volatile("s_waitcnt vmcnt(0)" ::: "memory");
        __syncthreads();
        for (int kk = 0; kk < 2; ++kk) {
            bf16x8 af[4], bfm[4];
            for (int x = 0; x < 4; ++x) {
                int ra = wr * 64 + x * 16 + lr;
                af[x] = *(const bf16x8*)(ldsA + ra * 64 + (((kk * 4 + lg) ^ (ra & 7)) * 8));
            }
            for (int x = 0; x < 4; ++x) {
                int rb = wc * 64 + x * 16 + lr;
                bfm[x] = *(const bf16x8*)(ldsB1 + rb * 64 + (((kk * 4 + lg) ^ (rb & 7)) * 8));
            }
            for (int mi = 0; mi < 4; ++mi)
                for (int ni = 0; ni < 4; ++ni)
                    acc1[mi][ni] = __builtin_amdgcn_mfma_f32_16x16x32_bf16(
                        af[mi], bfm[ni], acc1[mi][ni], 0, 0, 0);
            for (int x = 0; x < 4; ++x) {
                int rb = wc * 64 + x * 16 + lr;
                bfm[x] = *(const bf16x8*)(ldsB2 + rb * 64 + (((kk * 4 + lg) ^ (rb & 7)) * 8));
            }
            for (int mi = 0; mi < 4; ++mi)
                for (int ni = 0; ni < 4; ++ni)
                    acc2[mi][ni] = __builtin_amdgcn_mfma_f32_16x16x32_bf16(
                        af[mi], bfm[ni], acc2[mi][ni], 0, 0, 0);
            for (int x = 0; x < 4; ++x) {
                int rb = wc * 64 + x * 16 + lr;
                bfm[x] = *(const bf16x8*)(ldsB3 + rb * 64 + (((kk * 4 + lg) ^ (rb & 7)) * 8));
            }
            for (int mi = 0; mi < 4; ++mi)
                for (int ni = 0; ni < 4; ++ni)
                    acc3[mi][ni] = __builtin_amdgcn_mfma_f32_16x16x32_bf16(
                        af[mi], bfm[ni], acc3[mi][ni], 0, 0, 0);
        }
        __syncthreads();
    }

    for (int mi = 0; mi < 4; ++mi) {
        int mbase = m0 + wr * 64 + mi * 16 + lg * 4;
        for (int ni = 0; ni < 4; ++ni) {
            int n = n0 + wc * 64 + ni * 16 + lr;
            f32x4 v1 = acc1[mi][ni];
            f32x4 v2 = acc2[mi][ni];
            f32x4 v3 = acc3[mi][ni];
            for (int r = 0; r < 4; ++r) {
                size_t idx = (size_t)(mbase + r) * N + n;
                out1[idx] = (bf16_t)v1[r];
                out2[idx] = (bf16_t)v2[r];
                out3[idx] = (bf16_t)v3[r];
            }
        }
    }
}

// ---------------- Dual-B GEMM (gate/up): silu(acc1)*acc2 epilogue ----------------
__global__ __launch_bounds__(256, 2) void gemm_dual(const bf16_t* __restrict__ A,
                                                    const bf16_t* __restrict__ B1,
                                                    const bf16_t* __restrict__ B2,
                                                    bf16_t* __restrict__ out1,
                                                    int M, int N, int K) {
    __shared__ __align__(16) bf16_t ldsA[128 * 64];
    __shared__ __align__(16) bf16_t ldsB1[128 * 64];
    __shared__ __align__(16) bf16_t ldsB2[128 * 64];
    int tid = threadIdx.x, lane = tid & 63, w = tid >> 6;
    int lr = lane & 15, lg = lane >> 4;

    int GX = gridDim.x, GYd = gridDim.y;
    int bid = blockIdx.y * GX + blockIdx.x;
    int nwg = GX * GYd;
    int qc = nwg >> 3, rc = nwg & 7;
    int xcd = bid & 7, jj = bid >> 3;
    int wg = (xcd < rc ? xcd * (qc + 1) : rc * (qc + 1) + (xcd - rc) * qc) + jj;
    int bx = wg / GYd;
    int by = wg % GYd;

    int m0 = by * 128, n0 = bx * 128;
    int wr = w >> 1, wc = w & 1;
    f32x4 acc1[4][4] = {};
    f32x4 acc2[4][4] = {};
    int srow = w * 8 + (lane >> 3);  // 0..31
    int sslot = lane & 7;

    for (int kt = 0; kt < K; kt += 64) {
        for (int i = 0; i < 4; ++i) {
            int row = i * 32 + srow;
            int sp = sslot ^ (row & 7);
            gload_lds16(A  + (size_t)(m0 + row) * K + kt + sp * 8, ldsA  + i * 2048 + w * 512);
            gload_lds16(B1 + (size_t)(n0 + row) * K + kt + sp * 8, ldsB1 + i * 2048 + w * 512);
            gload_lds16(B2 + (size_t)(n0 + row) * K + kt + sp * 8, ldsB2 + i * 2048 + w * 512);
        }
        asm volatile("s_waitcnt vmcnt(0)" ::: "memory");
        __syncthreads();
        for (int kk = 0; kk < 2; ++kk) {
            bf16x8 af[4], bfm[4];
            for (int x = 0; x < 4; ++x) {
                int ra = wr * 64 + x * 16 + lr;
                af[x] = *(const bf16x8*)(ldsA + ra * 64 + (((kk * 4 + lg) ^ (ra & 7)) * 8));
            }
            for (int x = 0; x < 4; ++x) {
                int rb = wc * 64 + x * 16 + lr;
                bfm[x] = *(const bf16x8*)(ldsB1 + rb * 64 + (((kk * 4 + lg) ^ (rb & 7)) * 8));
            }
            for (int mi = 0; mi < 4; ++mi)
                for (int ni = 0; ni < 4; ++ni)
                    acc1[mi][ni] = __builtin_amdgcn_mfma_f32_16x16x32_bf16(
                        af[mi], bfm[ni], acc1[mi][ni], 0, 0, 0);
            for (int x = 0; x < 4; ++x) {
                int rb = wc * 64 + x * 16 + lr;
                bfm[x] = *(const bf16x8*)(ldsB2 + rb * 64 + (((kk * 4 + lg) ^ (rb & 7)) * 8));
            }
            for (int mi = 0; mi < 4; ++mi)
                for (int ni = 0; ni < 4; ++ni)
                    acc2[mi][ni] = __builtin_amdgcn_mfma_f32_16x16x32_bf16(
                        af[mi], bfm[ni], acc2[mi][ni], 0, 0, 0);
        }
        __syncthreads();
    }

    for (int mi = 0; mi < 4; ++mi) {
        int mbase = m0 + wr * 64 + mi * 16 + lg * 4;
        for (int ni = 0; ni < 4; ++ni) {
            int n = n0 + wc * 64 + ni * 16 + lr;
            f32x4 v1 = acc1[mi][ni];
            f32x4 v2 = acc2[mi][ni];
            for (int r = 0; r < 4; ++r) {
                size_t idx = (size_t)(mbase + r) * N + n;
                float g = v1[r];
                float sg = g / (1.0f + __expf(-g));
                out1[idx] = (bf16_t)(sg * v2[r]);
            }
        }
    }
}

// ---------------- Flash attention v3 (causal): 32 q-rows/wave, KVBLK=64 ----------------
// One K-frag / V-frag LDS read feeds 2 MFMAs (qt in {0,1}); block covers 128 q-rows.
__global__ __launch_bounds__(256, 2) void attn_k(const bf16_t* __restrict__ qb,
                                                 const bf16_t* __restrict__ kb,
                                                 const bf16_t* __restrict__ vtb,
                                                 bf16_t* __restrict__ ab) {
    __shared__ __align__(16) bf16_t ldsK[64 * 128];   // 16 KB, src-swizzled slots
    __shared__ __align__(16) bf16_t ldsVt[128 * 64];  // 16 KB, src-swizzled slots
    __shared__ __align__(16) float pbuf[4][32][68];   // 34 KB, per wave [q 0..31][k 0..63]
    int bid = blockIdx.x;
    int band = 15 - (bid >> 5);      // 16 bands of 128 q-rows, heavy-first
    int bh = bid & 31;
    int b = bh >> 4, h = bh & 15;
    int q0 = band * 128;
    int tid = threadIdx.x, lane = tid & 63, w = tid >> 6;
    int lr = lane & 15, lg = lane >> 4;
    size_t kqbase = ((size_t)b * SS) * DD + h * HDIM;
    size_t vtbase = ((size_t)(b * HH + h)) * HDIM * SS;
    int qw = q0 + w * 32;            // wave covers q-rows [qw, qw+32)

    bf16x8 aq[2][4];
    #pragma unroll
    for (int qt = 0; qt < 2; ++qt)
        #pragma unroll
        for (int kd = 0; kd < 4; ++kd)
            aq[qt][kd] = *(const bf16x8*)(qb + kqbase +
                (size_t)(qw + qt * 16 + lr) * DD + kd * 32 + lg * 8);

    f32x4 acc[2][8] = {};
    float mrun[2][4], lrun[2][4];
    #pragma unroll
    for (int qt = 0; qt < 2; ++qt)
        #pragma unroll
        for (int r = 0; r < 4; ++r) { mrun[qt][r] = -1e30f; lrun[qt][r] = 0.f; }
    const float scale = 0.08838834764831845f;  // 1/sqrt(128)
    int ntiles = 2 * band + 2;

    for (int t = 0; t < ntiles; ++t) {
        int kk0 = t * 64;
        #pragma unroll
        for (int it = 0; it < 4; ++it) {
            int cid = it * 256 + tid;
            int kr = cid >> 4, kslot = cid & 15;
            gload_lds16(kb + kqbase + (size_t)(kk0 + kr) * DD + ((kslot ^ (kr & 7)) * 8),
                        ldsK + it * 2048 + w * 512);
            int vd = cid >> 3, vslot = cid & 7;
            gload_lds16(vtb + vtbase + (size_t)vd * SS + kk0 + ((vslot ^ (vd & 7)) * 8),
                        ldsVt + it * 2048 + w * 512);
        }
        asm volatile("s_waitcnt vmcnt(0)" ::: "memory");
        __syncthreads();

        // QK^T: one bk read feeds both q-fragments
        f32x4 sf[2][4];
        #pragma unroll
        for (int nf = 0; nf < 4; ++nf) {
            f32x4 d0 = {}, d1 = {};
            int row = nf * 16 + lr;
            #pragma unroll
            for (int kd = 0; kd < 4; ++kd) {
                bf16x8 bk = *(const bf16x8*)(ldsK + row * 128 +
                                             (((kd * 4 + lg) ^ (lr & 7)) * 8));
                d0 = __builtin_amdgcn_mfma_f32_16x16x32_bf16(aq[0][kd], bk, d0, 0, 0, 0);
                d1 = __builtin_amdgcn_mfma_f32_16x16x32_bf16(aq[1][kd], bk, d1, 0, 0, 0);
            }
            sf[0][nf] = d0; sf[1][nf] = d1;
        }
        #pragma unroll
        for (int qt = 0; qt < 2; ++qt) {
            #pragma unroll
            for (int r = 0; r < 4; ++r) {
                int qg = qw + qt * 16 + lg * 4 + r;
                float s[4];
                #pragma unroll
                for (int nf = 0; nf < 4; ++nf) {
                    s[nf] = sf[qt][nf][r] * scale;
                    if (kk0 + nf * 16 + lr > qg) s[nf] = -1e30f;
                }
                float mx = fmaxf(fmaxf(s[0], s[1]), fmaxf(s[2], s[3]));
                mx = fmaxf(mx, __shfl_xor(mx, 1));
                mx = fmaxf(mx, __shfl_xor(mx, 2));
                mx = fmaxf(mx, __shfl_xor(mx, 4));
                mx = fmaxf(mx, __shfl_xor(mx, 8));
                float mnew = fmaxf(mrun[qt][r], mx);
                float rs = 0.f;
                #pragma unroll
                for (int nf = 0; nf < 4; ++nf) {
                    float p = __expf(s[nf] - mnew);
                    rs += p;
                    pbuf[w][qt * 16 + lg * 4 + r][nf * 16 + (lr ^ (r << 2))] = p;
                }
                rs += __shfl_xor(rs, 1); rs += __shfl_xor(rs, 2);
                rs += __shfl_xor(rs, 4); rs += __shfl_xor(rs, 8);
                float corr = __expf(mrun[qt][r] - mnew);
                lrun[qt][r] = lrun[qt][r] * corr + rs;
                mrun[qt][r] = mnew;
                #pragma unroll
                for (int df = 0; df < 8; ++df) acc[qt][df][r] *= corr;
            }
        }
        asm volatile("s_waitcnt lgkmcnt(0)" ::: "memory");
        // PV: one bv read feeds both q-fragments
        #pragma unroll
        for (int ks2 = 0; ks2 < 2; ++ks2) {
            int nfA = ks2 * 2 + (lg >> 1);
            int off = (lg & 1) * 8;
            int sw = (lr & 3) << 2;
            bf16x8 ap[2];
            #pragma unroll
            for (int qt = 0; qt < 2; ++qt) {
                float4 a0 = *(const float4*)&pbuf[w][qt * 16 + lr][nfA * 16 + (off ^ sw)];
                float4 a1 = *(const float4*)&pbuf[w][qt * 16 + lr][nfA * 16 + ((off + 4) ^ sw)];
                ap[qt][0] = (bf16_t)a0.x; ap[qt][1] = (bf16_t)a0.y;
                ap[qt][2] = (bf16_t)a0.z; ap[qt][3] = (bf16_t)a0.w;
                ap[qt][4] = (bf16_t)a1.x; ap[qt][5] = (bf16_t)a1.y;
                ap[qt][6] = (bf16_t)a1.z; ap[qt][7] = (bf16_t)a1.w;
            }
            #pragma unroll
            for (int df = 0; df < 8; ++df) {
                bf16x8 bv = *(const bf16x8*)(ldsVt + (df * 16 + lr) * 64 +
                                             (((ks2 * 4 + lg) ^ (lr & 7)) * 8));
                acc[0][df] = __builtin_amdgcn_mfma_f32_16x16x32_bf16(ap[0], bv, acc[0][df], 0, 0, 0);
                acc[1][df] = __builtin_amdgcn_mfma_f32_16x16x32_bf16(ap[1], bv, acc[1][df], 0, 0, 0);
            }
        }
        __syncthreads();
    }
    #pragma unroll
    for (int qt = 0; qt < 2; ++qt)
        #pragma unroll
        for (int df = 0; df < 8; ++df)
            #pragma unroll
            for (int r = 0; r < 4; ++r) {
                int qg = qw + qt * 16 + lg * 4 + r;
                ab[kqbase + (size_t)qg * DD + df * 16 + lr] =
                    (bf16_t)(acc[qt][df][r] / lrun[qt][r]);
            }
}

extern "C" void kernel_launch(void* const* d_in, const int* in_sizes, int n_in,
                              void* d_out, int out_size, void* d_ws, size_t ws_size,
                              hipStream_t stream) {
    const float* hs  = (const float*)d_in[0];
    // d_in[1] = attention_mask (exactly causal) — applied analytically
    const float* Wq  = (const float*)d_in[2];
    const float* Wk  = (const float*)d_in[3];
    const float* Wv  = (const float*)d_in[4];
    const float* Wo  = (const float*)d_in[5];
    const float* Wg  = (const float*)d_in[6];
    const float* Wu  = (const float*)d_in[7];
    const float* Wd  = (const float*)d_in[8];
    const float* ln1 = (const float*)d_in[9];
    const float* ln2 = (const float*)d_in[10];

    char* ws = (char*)d_ws;
    const size_t MB = 1u << 20;
    bf16_t* xb     = (bf16_t*)(ws);                 // 16 MiB [M][D]
    bf16_t* qb     = (bf16_t*)(ws + 16 * MB);       // 16 MiB
    bf16_t* kb     = (bf16_t*)(ws + 32 * MB);       // 16 MiB
    bf16_t* vb     = (bf16_t*)(ws + 48 * MB);       // 16 MiB
    bf16_t* vtb    = (bf16_t*)(ws + 64 * MB);       // 16 MiB (dead before hidden is written)
    float*  cosb   = (float*)(ws + 80 * MB);        // 1 MiB (dead before hidden is written)
    float*  sinb   = (float*)(ws + 81 * MB);        // 1 MiB
    float*  hidden = (float*)(ws + 64 * MB);        // 32 MiB f32, written at Wo step
    bf16_t* wtA    = (bf16_t*)(ws + 96 * MB);       // 23.5 MiB weight scratch A (fits 2x 8MB)
    bf16_t* wtA2   = wtA + (size_t)DD * DD;         // second panel within wtA
    bf16_t* wtB    = (bf16_t*)d_out;                // d_out (32 MiB) as scratch B until final gemm
    bf16_t* ab = xb;   // attn out reuses xb
    bf16_t* yb = xb;   // ln2 out reuses xb
    bf16_t* gb = qb;   // h = silu(gate)*up [M][I] = 43 MiB, reuses q/k/v region

    if (ws_size < (size_t)(98 * MB) + (size_t)II * DD * 2) return;

    // 1. LN1
    rmsnorm_k<<<MM, 256, 0, stream>>>(hs, ln1, xb);
    // 2. RoPE tables
    rope_tables_k<<<SS, 128, 0, stream>>>(cosb, sinb);
    // 3-6. QKV fused (shared A-tile) — triple-B GEMM
    convT_k<<<dim3(DD / 32, DD / 32), 256, 0, stream>>>(Wq, wtA, DD, DD);
    convT_k<<<dim3(DD / 32, DD / 32), 256, 0, stream>>>(Wk, wtA2, DD, DD);
    convT_k<<<dim3(DD / 32, DD / 32), 256, 0, stream>>>(Wv, wtB, DD, DD);
    gemm_tri<<<dim3(DD / 128, MM / 128), 256, 0, stream>>>(xb, wtA, wtA2, wtB, qb, kb, vb, MM, DD, DD);
    // 7. V transpose for attention B-operand staging
    vtrans_k<<<dim3(DD / 32, SS / 32, BB), 256, 0, stream>>>(vb, vtb);
    // 8. RoPE on q,k
    rope_apply_k<<<(MM * HH * 64) / 256, 256, 0, stream>>>(qb, kb, cosb, sinb);
    // 9. attention (v3: 128 q-rows per block, 512 blocks)
    attn_k<<<512, 256, 0, stream>>>(qb, kb, vtb, ab);
    // 10-11. Wo + residual -> hidden (f32; overwrites vtb/cos/sin, all dead)
    convT_k<<<dim3(DD / 32, DD / 32), 256, 0, stream>>>(Wo, wtA, DD, DD);
    gemm_bt<1><<<dim3(DD / 128, MM / 128), 256, 0, stream>>>(ab, wtA, hidden, hs, MM, DD, DD);
    // 12. LN2
    rmsnorm_k<<<MM, 256, 0, stream>>>(hidden, ln2, yb);
    // 13-15. gate & up fused (shared A-tile) + silu-mul epilogue -> gb
    convT_k<<<dim3(II / 32, DD / 32), 256, 0, stream>>>(Wg, wtA, DD, II);
    convT_k<<<dim3(II / 32, DD / 32), 256, 0, stream>>>(Wu, wtB, DD, II);
    gemm_dual<<<dim3(II / 128, MM / 128), 256, 0, stream>>>(yb, wtA, wtB, gb, MM, II, DD);
    // 16-17. out = hidden + h @ Wd (f32; overwrites wtB scratch = d_out, now dead)
    convT_k<<<dim3(DD / 32, II / 32), 256, 0, stream>>>(Wd, wtA, II, DD);
    gemm_bt<1><<<dim3(DD / 128, MM / 128), 256, 0, stream>>>(gb, wtA, (float*)d_out, hidden, MM, DD, II);
}

// Round 14
// 638.274 us; speedup vs baseline: 1.0531x; 1.0531x over previous
//
#include <hip/hip_runtime.h>
#include <hip/hip_bf16.h>
#include <cmath>

typedef __bf16 bf16_t;
typedef __bf16 bf16x8 __attribute__((ext_vector_type(8)));
typedef float f32x4 __attribute__((ext_vector_type(4)));

#define DEV __device__ __forceinline__

static constexpr int BB = 2, SS = 2048, DD = 2048, HH = 16, HDIM = 128, II = 5504;
static constexpr int MM = BB * SS; // 4096

DEV void gload_lds16(const void* g, void* l) {
    __builtin_amdgcn_global_load_lds(
        (__attribute__((address_space(1))) void*)const_cast<void*>(g),
        (__attribute__((address_space(3))) void*)l, 16, 0, 0);
}

// ---------------- RMSNorm: f32 in -> bf16 out ----------------
__global__ __launch_bounds__(256) void rmsnorm_k(const float* __restrict__ x,
                                                 const float* __restrict__ w,
                                                 bf16_t* __restrict__ out) {
    int row = blockIdx.x;
    int t = threadIdx.x;
    const float4* xr = (const float4*)(x + (size_t)row * DD);
    float4 a = xr[t];
    float4 b = xr[t + 256];
    float ss = a.x * a.x + a.y * a.y + a.z * a.z + a.w * a.w +
               b.x * b.x + b.y * b.y + b.z * b.z + b.w * b.w;
    for (int m = 1; m < 64; m <<= 1) ss += __shfl_xor(ss, m);
    __shared__ float red[4];
    int lane = t & 63, wv = t >> 6;
    if (lane == 0) red[wv] = ss;
    __syncthreads();
    float scale = rsqrtf((red[0] + red[1] + red[2] + red[3]) * (1.0f / DD) + 1e-6f);
    const float4* w4 = (const float4*)w;
    float4 wa = w4[t], wb = w4[t + 256];
    bf16_t* o = out + (size_t)row * DD;
    union { bf16_t h[4]; ushort4 u; } pa, pb;
    pa.h[0] = (bf16_t)(a.x * scale * wa.x); pa.h[1] = (bf16_t)(a.y * scale * wa.y);
    pa.h[2] = (bf16_t)(a.z * scale * wa.z); pa.h[3] = (bf16_t)(a.w * scale * wa.w);
    pb.h[0] = (bf16_t)(b.x * scale * wb.x); pb.h[1] = (bf16_t)(b.y * scale * wb.y);
    pb.h[2] = (bf16_t)(b.z * scale * wb.z); pb.h[3] = (bf16_t)(b.w * scale * wb.w);
    ((ushort4*)o)[t] = pa.u;
    ((ushort4*)o)[t + 256] = pb.u;
}

// ---------------- RoPE tables ----------------
__global__ void rope_tables_k(float* __restrict__ cosb, float* __restrict__ sinb) {
    int s = blockIdx.x;
    int d = threadIdx.x;       // 0..127
    int j = d & 63;
    float inv = powf(10000.0f, -(2.0f * (float)j) / 128.0f);
    float ang = (float)s * inv;
    cosb[s * HDIM + d] = cosf(ang);
    sinb[s * HDIM + d] = sinf(ang);
}

// ---------------- RoPE apply (in-place on q and k, bf16) ----------------
__global__ __launch_bounds__(256) void rope_apply_k(bf16_t* __restrict__ q,
                                                    bf16_t* __restrict__ k,
                                                    const float* __restrict__ cosb,
                                                    const float* __restrict__ sinb) {
    int t = blockIdx.x * 256 + threadIdx.x;   // [0, M*H*64)
    int j = t & 63;
    int h = (t >> 6) & 15;
    int m = t >> 10;          // 0..4095
    int s = m & (SS - 1);
    size_t idx = (size_t)m * DD + h * HDIM + j;
    float c = cosb[s * HDIM + j];
    float sn = sinb[s * HDIM + j];
    float q1 = (float)q[idx], q2 = (float)q[idx + 64];
    q[idx]      = (bf16_t)(q1 * c - q2 * sn);
    q[idx + 64] = (bf16_t)(q2 * c + q1 * sn);
    float k1 = (float)k[idx], k2 = (float)k[idx + 64];
    k[idx]      = (bf16_t)(k1 * c - k2 * sn);
    k[idx + 64] = (bf16_t)(k2 * c + k1 * sn);
}

// ---------------- convert + transpose: W[K][N] f32 -> Wt[N][K] bf16 ----------------
__global__ __launch_bounds__(256) void convT_k(const float* __restrict__ W,
                                               bf16_t* __restrict__ Wt,
                                               int K, int N) {
    __shared__ float tile[32][33];
    int n0 = blockIdx.x * 32, k0 = blockIdx.y * 32;
    int tx = threadIdx.x & 31, ty = threadIdx.x >> 5;  // ty 0..7
    for (int i = 0; i < 4; ++i)
        tile[ty + 8 * i][tx] = W[(size_t)(k0 + ty + 8 * i) * N + n0 + tx];
    __syncthreads();
    for (int i = 0; i < 4; ++i)
        Wt[(size_t)(n0 + ty + 8 * i) * K + k0 + tx] = (bf16_t)tile[tx][ty + 8 * i];
}

// ---------------- V transpose: vb[b][s][hd] bf16 -> vtb[b][hd][s] bf16 ----------------
__global__ __launch_bounds__(256) void vtrans_k(const bf16_t* __restrict__ vbp,
                                                bf16_t* __restrict__ vtb) {
    __shared__ ushort tile[32][33];
    int b = blockIdx.z;
    int s0 = blockIdx.y * 32, c0 = blockIdx.x * 32;
    int tx = threadIdx.x & 31, ty = threadIdx.x >> 5;  // ty 0..7
    const ushort* in = (const ushort*)vbp + (size_t)b * SS * DD;
    ushort* out = (ushort*)vtb + (size_t)b * DD * SS;
    for (int i = 0; i < 4; ++i)
        tile[ty + 8 * i][tx] = in[(size_t)(s0 + ty + 8 * i) * DD + c0 + tx];
    __syncthreads();
    for (int i = 0; i < 4; ++i)
        out[(size_t)(c0 + ty + 8 * i) * SS + s0 + tx] = tile[tx][ty + 8 * i];
}

// ---------------- GEMM (r5-proven): C[M][N] = A[M][K] * Bt[N][K]^T ----------------
// EPI 0: bf16 store. EPI 1: f32 store = res + acc.
template <int EPI>
__global__ __launch_bounds__(256, 2) void gemm_bt(const bf16_t* __restrict__ A,
                                                  const bf16_t* __restrict__ Bt,
                                                  void* __restrict__ outp,
                                                  const float* __restrict__ res,
                                                  int M, int N, int K) {
    __shared__ __align__(16) bf16_t ldsA[128 * 64];
    __shared__ __align__(16) bf16_t ldsB[128 * 64];
    int tid = threadIdx.x, lane = tid & 63, w = tid >> 6;
    int lr = lane & 15, lg = lane >> 4;

    int GX = gridDim.x, GYd = gridDim.y;
    int bid = blockIdx.y * GX + blockIdx.x;
    int nwg = GX * GYd;
    int qc = nwg >> 3, rc = nwg & 7;
    int xcd = bid & 7, jj = bid >> 3;
    int wg = (xcd < rc ? xcd * (qc + 1) : rc * (qc + 1) + (xcd - rc) * qc) + jj;
    int bx = wg / GYd;
    int by = wg % GYd;

    int m0 = by * 128, n0 = bx * 128;
    int wr = w >> 1, wc = w & 1;
    f32x4 acc[4][4] = {};
    int srow = w * 8 + (lane >> 3);  // 0..31
    int sslot = lane & 7;

    for (int kt = 0; kt < K; kt += 64) {
        for (int i = 0; i < 4; ++i) {
            int row = i * 32 + srow;
            int sp = sslot ^ (row & 7);
            gload_lds16(A + (size_t)(m0 + row) * K + kt + sp * 8,
                        ldsA + i * 2048 + w * 512);
            gload_lds16(Bt + (size_t)(n0 + row) * K + kt + sp * 8,
                        ldsB + i * 2048 + w * 512);
        }
        asm volatile("s_waitcnt vmcnt(0)" ::: "memory");
        __syncthreads();
        for (int kk = 0; kk < 2; ++kk) {
            bf16x8 af[4], bfm[4];
            for (int x = 0; x < 4; ++x) {
                int ra = wr * 64 + x * 16 + lr;
                int sa = (kk * 4 + lg) ^ (ra & 7);
                af[x] = *(const bf16x8*)(ldsA + ra * 64 + sa * 8);
                int rb = wc * 64 + x * 16 + lr;
                int sb = (kk * 4 + lg) ^ (rb & 7);
                bfm[x] = *(const bf16x8*)(ldsB + rb * 64 + sb * 8);
            }
            for (int mi = 0; mi < 4; ++mi)
                for (int ni = 0; ni < 4; ++ni)
                    acc[mi][ni] = __builtin_amdgcn_mfma_f32_16x16x32_bf16(
                        af[mi], bfm[ni], acc[mi][ni], 0, 0, 0);
        }
        __syncthreads();
    }

    for (int mi = 0; mi < 4; ++mi) {
        int mbase = m0 + wr * 64 + mi * 16 + lg * 4;
        for (int ni = 0; ni < 4; ++ni) {
            int n = n0 + wc * 64 + ni * 16 + lr;
            f32x4 v = acc[mi][ni];
            for (int r = 0; r < 4; ++r) {
                size_t idx = (size_t)(mbase + r) * N + n;
                if (EPI == 0) ((bf16_t*)outp)[idx] = (bf16_t)v[r];
                else          ((float*)outp)[idx] = res[idx] + v[r];
            }
        }
    }
}

// ---------------- Dual-B GEMM: one A-tile, two B-panels, two accumulators ----------------
// EPI 0 (QK): out1=bf16(acc1), out2=bf16(acc2).
// EPI 1 (gate/up): out1 = bf16( silu(acc1) * acc2 ).
template <int EPI>
__global__ __launch_bounds__(256, 2) void gemm_dual(const bf16_t* __restrict__ A,
                                                    const bf16_t* __restrict__ B1,
                                                    const bf16_t* __restrict__ B2,
                                                    bf16_t* __restrict__ out1,
                                                    bf16_t* __restrict__ out2,
                                                    int M, int N, int K) {
    __shared__ __align__(16) bf16_t ldsA[128 * 64];
    __shared__ __align__(16) bf16_t ldsB1[128 * 64];
    __shared__ __align__(16) bf16_t ldsB2[128 * 64];
    int tid = threadIdx.x, lane = tid & 63, w = tid >> 6;
    int lr = lane & 15, lg = lane >> 4;

    int GX = gridDim.x, GYd = gridDim.y;
    int bid = blockIdx.y * GX + blockIdx.x;
    int nwg = GX * GYd;
    int qc = nwg >> 3, rc = nwg & 7;
    int xcd = bid & 7, jj = bid >> 3;
    int wg = (xcd < rc ? xcd * (qc + 1) : rc * (qc + 1) + (xcd - rc) * qc) + jj;
    int bx = wg / GYd;
    int by = wg % GYd;

    int m0 = by * 128, n0 = bx * 128;
    int wr = w >> 1, wc = w & 1;
    f32x4 acc1[4][4] = {};
    f32x4 acc2[4][4] = {};
    int srow = w * 8 + (lane >> 3);  // 0..31
    int sslot = lane & 7;

    for (int kt = 0; kt < K; kt += 64) {
        for (int i = 0; i < 4; ++i) {
            int row = i * 32 + srow;
            int sp = sslot ^ (row & 7);
            gload_lds16(A  + (size_t)(m0 + row) * K + kt + sp * 8, ldsA  + i * 2048 + w * 512);
            gload_lds16(B1 + (size_t)(n0 + row) * K + kt + sp * 8, ldsB1 + i * 2048 + w * 512);
            gload_lds16(B2 + (size_t)(n0 + row) * K + kt + sp * 8, ldsB2 + i * 2048 + w * 512);
        }
        asm volatile("s_waitcnt vmcnt(0)" ::: "memory");
        __syncthreads();
        for (int kk = 0; kk < 2; ++kk) {
            bf16x8 af[4], bfm[4];
            for (int x = 0; x < 4; ++x) {
                int ra = wr * 64 + x * 16 + lr;
                af[x] = *(const bf16x8*)(ldsA + ra * 64 + (((kk * 4 + lg) ^ (ra & 7)) * 8));
            }
            for (int x = 0; x < 4; ++x) {
                int rb = wc * 64 + x * 16 + lr;
                bfm[x] = *(const bf16x8*)(ldsB1 + rb * 64 + (((kk * 4 + lg) ^ (rb & 7)) * 8));
            }
            for (int mi = 0; mi < 4; ++mi)
                for (int ni = 0; ni < 4; ++ni)
                    acc1[mi][ni] = __builtin_amdgcn_mfma_f32_16x16x32_bf16(
                        af[mi], bfm[ni], acc1[mi][ni], 0, 0, 0);
            for (int x = 0; x < 4; ++x) {
                int rb = wc * 64 + x * 16 + lr;
                bfm[x] = *(const bf16x8*)(ldsB2 + rb * 64 + (((kk * 4 + lg) ^ (rb & 7)) * 8));
            }
            for (int mi = 0; mi < 4; ++mi)
                for (int ni = 0; ni < 4; ++ni)
                    acc2[mi][ni] = __builtin_amdgcn_mfma_f32_16x16x32_bf16(
                        af[mi], bfm[ni], acc2[mi][ni], 0, 0, 0);
        }
        __syncthreads();
    }

    for (int mi = 0; mi < 4; ++mi) {
        int mbase = m0 + wr * 64 + mi * 16 + lg * 4;
        for (int ni = 0; ni < 4; ++ni) {
            int n = n0 + wc * 64 + ni * 16 + lr;
            f32x4 v1 = acc1[mi][ni];
            f32x4 v2 = acc2[mi][ni];
            for (int r = 0; r < 4; ++r) {
                size_t idx = (size_t)(mbase + r) * N + n;
                if (EPI == 0) {
                    out1[idx] = (bf16_t)v1[r];
                    out2[idx] = (bf16_t)v2[r];
                } else {
                    float g = v1[r];
                    float sg = g / (1.0f + __expf(-g));
                    out1[idx] = (bf16_t)(sg * v2[r]);
                }
            }
        }
    }
}

// ---------------- Flash attention v3 (causal): 32 q-rows/wave, KVBLK=64 ----------------
// One K-frag / V-frag LDS read feeds 2 MFMAs (qt in {0,1}); block covers 128 q-rows.
__global__ __launch_bounds__(256, 2) void attn_k(const bf16_t* __restrict__ qb,
                                                 const bf16_t* __restrict__ kb,
                                                 const bf16_t* __restrict__ vtb,
                                                 bf16_t* __restrict__ ab) {
    __shared__ __align__(16) bf16_t ldsK[64 * 128];   // 16 KB, src-swizzled slots
    __shared__ __align__(16) bf16_t ldsVt[128 * 64];  // 16 KB, src-swizzled slots
    __shared__ __align__(16) float pbuf[4][32][68];   // 34 KB, per wave [q 0..31][k 0..63]
    int bid = blockIdx.x;
    int band = 15 - (bid >> 5);      // 16 bands of 128 q-rows, heavy-first
    int bh = bid & 31;
    int b = bh >> 4, h = bh & 15;
    int q0 = band * 128;
    int tid = threadIdx.x, lane = tid & 63, w = tid >> 6;
    int lr = lane & 15, lg = lane >> 4;
    size_t kqbase = ((size_t)b * SS) * DD + h * HDIM;
    size_t vtbase = ((size_t)(b * HH + h)) * HDIM * SS;
    int qw = q0 + w * 32;            // wave covers q-rows [qw, qw+32)

    bf16x8 aq[2][4];
    #pragma unroll
    for (int qt = 0; qt < 2; ++qt)
        #pragma unroll
        for (int kd = 0; kd < 4; ++kd)
            aq[qt][kd] = *(const bf16x8*)(qb + kqbase +
                (size_t)(qw + qt * 16 + lr) * DD + kd * 32 + lg * 8);

    f32x4 acc[2][8] = {};
    float mrun[2][4], lrun[2][4];
    #pragma unroll
    for (int qt = 0; qt < 2; ++qt)
        #pragma unroll
        for (int r = 0; r < 4; ++r) { mrun[qt][r] = -1e30f; lrun[qt][r] = 0.f; }
    const float scale = 0.08838834764831845f;  // 1/sqrt(128)
    int ntiles = 2 * band + 2;

    for (int t = 0; t < ntiles; ++t) {
        int kk0 = t * 64;
        #pragma unroll
        for (int it = 0; it < 4; ++it) {
            int cid = it * 256 + tid;
            int kr = cid >> 4, kslot = cid & 15;
            gload_lds16(kb + kqbase + (size_t)(kk0 + kr) * DD + ((kslot ^ (kr & 7)) * 8),
                        ldsK + it * 2048 + w * 512);
            int vd = cid >> 3, vslot = cid & 7;
            gload_lds16(vtb + vtbase + (size_t)vd * SS + kk0 + ((vslot ^ (vd & 7)) * 8),
                        ldsVt + it * 2048 + w * 512);
        }
        asm volatile("s_waitcnt vmcnt(0)" ::: "memory");
        __syncthreads();

        // QK^T: one bk read feeds both q-fragments
        f32x4 sf[2][4];
        #pragma unroll
        for (int nf = 0; nf < 4; ++nf) {
            f32x4 d0 = {}, d1 = {};
            int row = nf * 16 + lr;
            #pragma unroll
            for (int kd = 0; kd < 4; ++kd) {
                bf16x8 bk = *(const bf16x8*)(ldsK + row * 128 +
                                             (((kd * 4 + lg) ^ (lr & 7)) * 8));
                d0 = __builtin_amdgcn_mfma_f32_16x16x32_bf16(aq[0][kd], bk, d0, 0, 0, 0);
                d1 = __builtin_amdgcn_mfma_f32_16x16x32_bf16(aq[1][kd], bk, d1, 0, 0, 0);
            }
            sf[0][nf] = d0; sf[1][nf] = d1;
        }
        #pragma unroll
        for (int qt = 0; qt < 2; ++qt) {
            #pragma unroll
            for (int r = 0; r < 4; ++r) {
                int qg = qw + qt * 16 + lg * 4 + r;
                float s[4];
                #pragma unroll
                for (int nf = 0; nf < 4; ++nf) {
                    s[nf] = sf[qt][nf][r] * scale;
                    if (kk0 + nf * 16 + lr > qg) s[nf] = -1e30f;
                }
                float mx = fmaxf(fmaxf(s[0], s[1]), fmaxf(s[2], s[3]));
                mx = fmaxf(mx, __shfl_xor(mx, 1));
                mx = fmaxf(mx, __shfl_xor(mx, 2));
                mx = fmaxf(mx, __shfl_xor(mx, 4));
                mx = fmaxf(mx, __shfl_xor(mx, 8));
                float mnew = fmaxf(mrun[qt][r], mx);
                float rs = 0.f;
                #pragma unroll
                for (int nf = 0; nf < 4; ++nf) {
                    float p = __expf(s[nf] - mnew);
                    rs += p;
                    pbuf[w][qt * 16 + lg * 4 + r][nf * 16 + (lr ^ (r << 2))] = p;
                }
                rs += __shfl_xor(rs, 1); rs += __shfl_xor(rs, 2);
                rs += __shfl_xor(rs, 4); rs += __shfl_xor(rs, 8);
                float corr = __expf(mrun[qt][r] - mnew);
                lrun[qt][r] = lrun[qt][r] * corr + rs;
                mrun[qt][r] = mnew;
                #pragma unroll
                for (int df = 0; df < 8; ++df) acc[qt][df][r] *= corr;
            }
        }
        asm volatile("s_waitcnt lgkmcnt(0)" ::: "memory");
        // PV: one bv read feeds both q-fragments
        #pragma unroll
        for (int ks2 = 0; ks2 < 2; ++ks2) {
            int nfA = ks2 * 2 + (lg >> 1);
            int off = (lg & 1) * 8;
            int sw = (lr & 3) << 2;
            bf16x8 ap[2];
            #pragma unroll
            for (int qt = 0; qt < 2; ++qt) {
                float4 a0 = *(const float4*)&pbuf[w][qt * 16 + lr][nfA * 16 + (off ^ sw)];
                float4 a1 = *(const float4*)&pbuf[w][qt * 16 + lr][nfA * 16 + ((off + 4) ^ sw)];
                ap[qt][0] = (bf16_t)a0.x; ap[qt][1] = (bf16_t)a0.y;
                ap[qt][2] = (bf16_t)a0.z; ap[qt][3] = (bf16_t)a0.w;
                ap[qt][4] = (bf16_t)a1.x; ap[qt][5] = (bf16_t)a1.y;
                ap[qt][6] = (bf16_t)a1.z; ap[qt][7] = (bf16_t)a1.w;
            }
            #pragma unroll
            for (int df = 0; df < 8; ++df) {
                bf16x8 bv = *(const bf16x8*)(ldsVt + (df * 16 + lr) * 64 +
                                             (((ks2 * 4 + lg) ^ (lr & 7)) * 8));
                acc[0][df] = __builtin_amdgcn_mfma_f32_16x16x32_bf16(ap[0], bv, acc[0][df], 0, 0, 0);
                acc[1][df] = __builtin_amdgcn_mfma_f32_16x16x32_bf16(ap[1], bv, acc[1][df], 0, 0, 0);
            }
        }
        __syncthreads();
    }
    #pragma unroll
    for (int qt = 0; qt < 2; ++qt)
        #pragma unroll
        for (int df = 0; df < 8; ++df)
            #pragma unroll
            for (int r = 0; r < 4; ++r) {
                int qg = qw + qt * 16 + lg * 4 + r;
                ab[kqbase + (size_t)qg * DD + df * 16 + lr] =
                    (bf16_t)(acc[qt][df][r] / lrun[qt][r]);
            }
}

extern "C" void kernel_launch(void* const* d_in, const int* in_sizes, int n_in,
                              void* d_out, int out_size, void* d_ws, size_t ws_size,
                              hipStream_t stream) {
    const float* hs  = (const float*)d_in[0];
    // d_in[1] = attention_mask (exactly causal) — applied analytically
    const float* Wq  = (const float*)d_in[2];
    const float* Wk  = (const float*)d_in[3];
    const float* Wv  = (const float*)d_in[4];
    const float* Wo  = (const float*)d_in[5];
    const float* Wg  = (const float*)d_in[6];
    const float* Wu  = (const float*)d_in[7];
    const float* Wd  = (const float*)d_in[8];
    const float* ln1 = (const float*)d_in[9];
    const float* ln2 = (const float*)d_in[10];

    char* ws = (char*)d_ws;
    const size_t MB = 1u << 20;
    bf16_t* xb     = (bf16_t*)(ws);                 // 16 MiB [M][D]
    bf16_t* qb     = (bf16_t*)(ws + 16 * MB);       // 16 MiB
    bf16_t* kb     = (bf16_t*)(ws + 32 * MB);       // 16 MiB
    bf16_t* vb     = (bf16_t*)(ws + 48 * MB);       // 16 MiB
    bf16_t* vtb    = (bf16_t*)(ws + 64 * MB);       // 16 MiB (dead before hidden is written)
    float*  cosb   = (float*)(ws + 80 * MB);        // 1 MiB (dead before hidden is written)
    float*  sinb   = (float*)(ws + 81 * MB);        // 1 MiB
    float*  hidden = (float*)(ws + 64 * MB);        // 32 MiB f32, written at Wo step
    bf16_t* wtA    = (bf16_t*)(ws + 96 * MB);       // 23.5 MiB transposed-weight scratch A
    bf16_t* wtB    = (bf16_t*)d_out;                // d_out (32 MiB) as scratch B until final gemm
    bf16_t* ab = xb;   // attn out reuses xb
    bf16_t* yb = xb;   // ln2 out reuses xb
    bf16_t* gb = qb;   // h = silu(gate)*up [M][I] = 43 MiB, reuses q/k/v region

    if (ws_size < (size_t)(98 * MB) + (size_t)II * DD * 2) return;

    // 1. LN1
    rmsnorm_k<<<MM, 256, 0, stream>>>(hs, ln1, xb);
    // 2. RoPE tables
    rope_tables_k<<<SS, 128, 0, stream>>>(cosb, sinb);
    // 3-5. Q & K fused (shared A-tile) — dual-B GEMM
    convT_k<<<dim3(DD / 32, DD / 32), 256, 0, stream>>>(Wq, wtA, DD, DD);
    convT_k<<<dim3(DD / 32, DD / 32), 256, 0, stream>>>(Wk, wtB, DD, DD);
    gemm_dual<0><<<dim3(DD / 128, MM / 128), 256, 0, stream>>>(xb, wtA, wtB, qb, kb, MM, DD, DD);
    // 6-7. V projection
    convT_k<<<dim3(DD / 32, DD / 32), 256, 0, stream>>>(Wv, wtA, DD, DD);
    gemm_bt<0><<<dim3(DD / 128, MM / 128), 256, 0, stream>>>(xb, wtA, vb, nullptr, MM, DD, DD);
    // 8. V transpose for attention B-operand staging
    vtrans_k<<<dim3(DD / 32, SS / 32, BB), 256, 0, stream>>>(vb, vtb);
    // 9. RoPE on q,k
    rope_apply_k<<<(MM * HH * 64) / 256, 256, 0, stream>>>(qb, kb, cosb, sinb);
    // 10. attention (v3: 128 q-rows per block, 512 blocks)
    attn_k<<<512, 256, 0, stream>>>(qb, kb, vtb, ab);
    // 11-12. Wo + residual -> hidden (f32; overwrites vtb/cos/sin, all dead)
    convT_k<<<dim3(DD / 32, DD / 32), 256, 0, stream>>>(Wo, wtA, DD, DD);
    gemm_bt<1><<<dim3(DD / 128, MM / 128), 256, 0, stream>>>(ab, wtA, hidden, hs, MM, DD, DD);
    // 13. LN2
    rmsnorm_k<<<MM, 256, 0, stream>>>(hidden, ln2, yb);
    // 14-16. gate & up fused (shared A-tile) + silu-mul epilogue -> gb
    convT_k<<<dim3(II / 32, DD / 32), 256, 0, stream>>>(Wg, wtA, DD, II);
    convT_k<<<dim3(II / 32, DD / 32), 256, 0, stream>>>(Wu, wtB, DD, II);
    gemm_dual<1><<<dim3(II / 128, MM / 128), 256, 0, stream>>>(yb, wtA, wtB, gb, nullptr, MM, II, DD);
    // 17-18. out = hidden + h @ Wd (f32; overwrites wtB scratch = d_out, now dead)
    convT_k<<<dim3(DD / 32, II / 32), 256, 0, stream>>>(Wd, wtA, II, DD);
    gemm_bt<1><<<dim3(DD / 128, MM / 128), 256, 0, stream>>>(gb, wtA, (float*)d_out, hidden, MM, DD, II);
}

// Round 15
// 612.150 us; speedup vs baseline: 1.0980x; 1.0427x over previous
//
#include <hip/hip_runtime.h>
#include <hip/hip_bf16.h>
#include <cmath>

typedef __bf16 bf16_t;
typedef __bf16 bf16x8 __attribute__((ext_vector_type(8)));
typedef float f32x4 __attribute__((ext_vector_type(4)));
typedef unsigned short ushort8 __attribute__((ext_vector_type(8)));

#define DEV __device__ __forceinline__

static constexpr int BB = 2, SS = 2048, DD = 2048, HH = 16, HDIM = 128, II = 5504;
static constexpr int MM = BB * SS; // 4096

DEV void gload_lds16(const void* g, void* l) {
    __builtin_amdgcn_global_load_lds(
        (__attribute__((address_space(1))) void*)const_cast<void*>(g),
        (__attribute__((address_space(3))) void*)l, 16, 0, 0);
}

// ---------------- RMSNorm: f32 in -> bf16 out ----------------
__global__ __launch_bounds__(256) void rmsnorm_k(const float* __restrict__ x,
                                                 const float* __restrict__ w,
                                                 bf16_t* __restrict__ out) {
    int row = blockIdx.x;
    int t = threadIdx.x;
    const float4* xr = (const float4*)(x + (size_t)row * DD);
    float4 a = xr[t];
    float4 b = xr[t + 256];
    float ss = a.x * a.x + a.y * a.y + a.z * a.z + a.w * a.w +
               b.x * b.x + b.y * b.y + b.z * b.z + b.w * b.w;
    for (int m = 1; m < 64; m <<= 1) ss += __shfl_xor(ss, m);
    __shared__ float red[4];
    int lane = t & 63, wv = t >> 6;
    if (lane == 0) red[wv] = ss;
    __syncthreads();
    float scale = rsqrtf((red[0] + red[1] + red[2] + red[3]) * (1.0f / DD) + 1e-6f);
    const float4* w4 = (const float4*)w;
    float4 wa = w4[t], wb = w4[t + 256];
    bf16_t* o = out + (size_t)row * DD;
    union { bf16_t h[4]; ushort4 u; } pa, pb;
    pa.h[0] = (bf16_t)(a.x * scale * wa.x); pa.h[1] = (bf16_t)(a.y * scale * wa.y);
    pa.h[2] = (bf16_t)(a.z * scale * wa.z); pa.h[3] = (bf16_t)(a.w * scale * wa.w);
    pb.h[0] = (bf16_t)(b.x * scale * wb.x); pb.h[1] = (bf16_t)(b.y * scale * wb.y);
    pb.h[2] = (bf16_t)(b.z * scale * wb.z); pb.h[3] = (bf16_t)(b.w * scale * wb.w);
    ((ushort4*)o)[t] = pa.u;
    ((ushort4*)o)[t + 256] = pb.u;
}

// ---------------- RoPE tables ----------------
__global__ void rope_tables_k(float* __restrict__ cosb, float* __restrict__ sinb) {
    int s = blockIdx.x;
    int d = threadIdx.x;       // 0..127
    int j = d & 63;
    float inv = powf(10000.0f, -(2.0f * (float)j) / 128.0f);
    float ang = (float)s * inv;
    cosb[s * HDIM + d] = cosf(ang);
    sinb[s * HDIM + d] = sinf(ang);
}

// ---------------- RoPE apply (in-place on q and k, bf16) ----------------
__global__ __launch_bounds__(256) void rope_apply_k(bf16_t* __restrict__ q,
                                                    bf16_t* __restrict__ k,
                                                    const float* __restrict__ cosb,
                                                    const float* __restrict__ sinb) {
    int t = blockIdx.x * 256 + threadIdx.x;   // [0, M*H*64)
    int j = t & 63;
    int h = (t >> 6) & 15;
    int m = t >> 10;          // 0..4095
    int s = m & (SS - 1);
    size_t idx = (size_t)m * DD + h * HDIM + j;
    float c = cosb[s * HDIM + j];
    float sn = sinb[s * HDIM + j];
    float q1 = (float)q[idx], q2 = (float)q[idx + 64];
    q[idx]      = (bf16_t)(q1 * c - q2 * sn);
    q[idx + 64] = (bf16_t)(q2 * c + q1 * sn);
    float k1 = (float)k[idx], k2 = (float)k[idx + 64];
    k[idx]      = (bf16_t)(k1 * c - k2 * sn);
    k[idx + 64] = (bf16_t)(k2 * c + k1 * sn);
}

// ---------------- convT v2: W[K][N] f32 -> Wt[N][K] bf16, 64x64 tile, vectorized ----------------
__global__ __launch_bounds__(256) void convT_k(const float* __restrict__ W,
                                               bf16_t* __restrict__ Wt,
                                               int K, int N) {
    __shared__ float tile[64][65];   // +1 pad: phase-2 reads ~2-way max (free)
    int n0 = blockIdx.x * 64, k0 = blockIdx.y * 64;
    int t = threadIdx.x;
    int r = t >> 4, cq = t & 15;     // phase 1: r 0..15, cq -> 4 floats
    #pragma unroll
    for (int it = 0; it < 4; ++it) {
        int row = it * 16 + r;
        float4 v = *(const float4*)(W + (size_t)(k0 + row) * N + n0 + cq * 4);
        tile[row][cq * 4 + 0] = v.x;
        tile[row][cq * 4 + 1] = v.y;
        tile[row][cq * 4 + 2] = v.z;
        tile[row][cq * 4 + 3] = v.w;
    }
    __syncthreads();
    int n = t >> 2, kq = t & 3;      // phase 2: n 0..63, 2 k-octs per thread
    #pragma unroll
    for (int it = 0; it < 2; ++it) {
        int k = (it * 4 + kq) * 8;
        union { bf16_t h[8]; ushort8 u; } p;
        #pragma unroll
        for (int j = 0; j < 8; ++j) p.h[j] = (bf16_t)tile[k + j][n];
        *(ushort8*)(Wt + (size_t)(n0 + n) * K + k0 + k) = p.u;
    }
}

// ---------------- V transpose v2: vb[b][s][c] -> vtb[b][c][s], 64x64, ushort8 both ways ----------------
__global__ __launch_bounds__(256) void vtrans_k(const bf16_t* __restrict__ vbp,
                                                bf16_t* __restrict__ vtb) {
    __shared__ ushort tile[64][70];  // pad 70: phase-2 gather ~2-way
    int b = blockIdx.z;
    int c0 = blockIdx.x * 64, s0 = blockIdx.y * 64;
    int t = threadIdx.x;
    const ushort* in = (const ushort*)vbp + (size_t)b * SS * DD;
    ushort* out = (ushort*)vtb + (size_t)b * DD * SS;
    int s = t >> 3, coct = t & 7;    // phase 1: s 0..31 (x2), 16B reads
    #pragma unroll
    for (int it = 0; it < 2; ++it) {
        int srow = it * 32 + s;
        ushort8 v = *(const ushort8*)(in + (size_t)(s0 + srow) * DD + c0 + coct * 8);
        #pragma unroll
        for (int j = 0; j < 8; ++j) tile[srow][coct * 8 + j] = v[j];
    }
    __syncthreads();
    int c = t >> 3, soct = t & 7;    // phase 2: c 0..31 (x2), 16B writes
    #pragma unroll
    for (int it = 0; it < 2; ++it) {
        int ccol = it * 32 + c;
        ushort8 v;
        #pragma unroll
        for (int j = 0; j < 8; ++j) v[j] = tile[soct * 8 + j][ccol];
        *(ushort8*)(out + (size_t)(c0 + ccol) * SS + s0 + soct * 8) = v;
    }
}

// ---------------- GEMM (r5-proven): C[M][N] = A[M][K] * Bt[N][K]^T ----------------
// EPI 0: bf16 store. EPI 1: f32 store = res + acc.
template <int EPI>
__global__ __launch_bounds__(256, 2) void gemm_bt(const bf16_t* __restrict__ A,
                                                  const bf16_t* __restrict__ Bt,
                                                  void* __restrict__ outp,
                                                  const float* __restrict__ res,
                                                  int M, int N, int K) {
    __shared__ __align__(16) bf16_t ldsA[128 * 64];
    __shared__ __align__(16) bf16_t ldsB[128 * 64];
    int tid = threadIdx.x, lane = tid & 63, w = tid >> 6;
    int lr = lane & 15, lg = lane >> 4;

    int GX = gridDim.x, GYd = gridDim.y;
    int bid = blockIdx.y * GX + blockIdx.x;
    int nwg = GX * GYd;
    int qc = nwg >> 3, rc = nwg & 7;
    int xcd = bid & 7, jj = bid >> 3;
    int wg = (xcd < rc ? xcd * (qc + 1) : rc * (qc + 1) + (xcd - rc) * qc) + jj;
    int bx = wg / GYd;
    int by = wg % GYd;

    int m0 = by * 128, n0 = bx * 128;
    int wr = w >> 1, wc = w & 1;
    f32x4 acc[4][4] = {};
    int srow = w * 8 + (lane >> 3);  // 0..31
    int sslot = lane & 7;

    for (int kt = 0; kt < K; kt += 64) {
        for (int i = 0; i < 4; ++i) {
            int row = i * 32 + srow;
            int sp = sslot ^ (row & 7);
            gload_lds16(A + (size_t)(m0 + row) * K + kt + sp * 8,
                        ldsA + i * 2048 + w * 512);
            gload_lds16(Bt + (size_t)(n0 + row) * K + kt + sp * 8,
                        ldsB + i * 2048 + w * 512);
        }
        asm volatile("s_waitcnt vmcnt(0)" ::: "memory");
        __syncthreads();
        for (int kk = 0; kk < 2; ++kk) {
            bf16x8 af[4], bfm[4];
            for (int x = 0; x < 4; ++x) {
                int ra = wr * 64 + x * 16 + lr;
                int sa = (kk * 4 + lg) ^ (ra & 7);
                af[x] = *(const bf16x8*)(ldsA + ra * 64 + sa * 8);
                int rb = wc * 64 + x * 16 + lr;
                int sb = (kk * 4 + lg) ^ (rb & 7);
                bfm[x] = *(const bf16x8*)(ldsB + rb * 64 + sb * 8);
            }
            for (int mi = 0; mi < 4; ++mi)
                for (int ni = 0; ni < 4; ++ni)
                    acc[mi][ni] = __builtin_amdgcn_mfma_f32_16x16x32_bf16(
                        af[mi], bfm[ni], acc[mi][ni], 0, 0, 0);
        }
        __syncthreads();
    }

    for (int mi = 0; mi < 4; ++mi) {
        int mbase = m0 + wr * 64 + mi * 16 + lg * 4;
        for (int ni = 0; ni < 4; ++ni) {
            int n = n0 + wc * 64 + ni * 16 + lr;
            f32x4 v = acc[mi][ni];
            for (int r = 0; r < 4; ++r) {
                size_t idx = (size_t)(mbase + r) * N + n;
                if (EPI == 0) ((bf16_t*)outp)[idx] = (bf16_t)v[r];
                else          ((float*)outp)[idx] = res[idx] + v[r];
            }
        }
    }
}

// ---------------- Dual-B GEMM: one A-tile, two B-panels, two accumulators ----------------
// EPI 0 (QK): out1=bf16(acc1), out2=bf16(acc2).
// EPI 1 (gate/up): out1 = bf16( silu(acc1) * acc2 ).
template <int EPI>
__global__ __launch_bounds__(256, 2) void gemm_dual(const bf16_t* __restrict__ A,
                                                    const bf16_t* __restrict__ B1,
                                                    const bf16_t* __restrict__ B2,
                                                    bf16_t* __restrict__ out1,
                                                    bf16_t* __restrict__ out2,
                                                    int M, int N, int K) {
    __shared__ __align__(16) bf16_t ldsA[128 * 64];
    __shared__ __align__(16) bf16_t ldsB1[128 * 64];
    __shared__ __align__(16) bf16_t ldsB2[128 * 64];
    int tid = threadIdx.x, lane = tid & 63, w = tid >> 6;
    int lr = lane & 15, lg = lane >> 4;

    int GX = gridDim.x, GYd = gridDim.y;
    int bid = blockIdx.y * GX + blockIdx.x;
    int nwg = GX * GYd;
    int qc = nwg >> 3, rc = nwg & 7;
    int xcd = bid & 7, jj = bid >> 3;
    int wg = (xcd < rc ? xcd * (qc + 1) : rc * (qc + 1) + (xcd - rc) * qc) + jj;
    int bx = wg / GYd;
    int by = wg % GYd;

    int m0 = by * 128, n0 = bx * 128;
    int wr = w >> 1, wc = w & 1;
    f32x4 acc1[4][4] = {};
    f32x4 acc2[4][4] = {};
    int srow = w * 8 + (lane >> 3);  // 0..31
    int sslot = lane & 7;

    for (int kt = 0; kt < K; kt += 64) {
        for (int i = 0; i < 4; ++i) {
            int row = i * 32 + srow;
            int sp = sslot ^ (row & 7);
            gload_lds16(A  + (size_t)(m0 + row) * K + kt + sp * 8, ldsA  + i * 2048 + w * 512);
            gload_lds16(B1 + (size_t)(n0 + row) * K + kt + sp * 8, ldsB1 + i * 2048 + w * 512);
            gload_lds16(B2 + (size_t)(n0 + row) * K + kt + sp * 8, ldsB2 + i * 2048 + w * 512);
        }
        asm volatile("s_waitcnt vmcnt(0)" ::: "memory");
        __syncthreads();
        for (int kk = 0; kk < 2; ++kk) {
            bf16x8 af[4], bfm[4];
            for (int x = 0; x < 4; ++x) {
                int ra = wr * 64 + x * 16 + lr;
                af[x] = *(const bf16x8*)(ldsA + ra * 64 + (((kk * 4 + lg) ^ (ra & 7)) * 8));
            }
            for (int x = 0; x < 4; ++x) {
                int rb = wc * 64 + x * 16 + lr;
                bfm[x] = *(const bf16x8*)(ldsB1 + rb * 64 + (((kk * 4 + lg) ^ (rb & 7)) * 8));
            }
            for (int mi = 0; mi < 4; ++mi)
                for (int ni = 0; ni < 4; ++ni)
                    acc1[mi][ni] = __builtin_amdgcn_mfma_f32_16x16x32_bf16(
                        af[mi], bfm[ni], acc1[mi][ni], 0, 0, 0);
            for (int x = 0; x < 4; ++x) {
                int rb = wc * 64 + x * 16 + lr;
                bfm[x] = *(const bf16x8*)(ldsB2 + rb * 64 + (((kk * 4 + lg) ^ (rb & 7)) * 8));
            }
            for (int mi = 0; mi < 4; ++mi)
                for (int ni = 0; ni < 4; ++ni)
                    acc2[mi][ni] = __builtin_amdgcn_mfma_f32_16x16x32_bf16(
                        af[mi], bfm[ni], acc2[mi][ni], 0, 0, 0);
        }
        __syncthreads();
    }

    for (int mi = 0; mi < 4; ++mi) {
        int mbase = m0 + wr * 64 + mi * 16 + lg * 4;
        for (int ni = 0; ni < 4; ++ni) {
            int n = n0 + wc * 64 + ni * 16 + lr;
            f32x4 v1 = acc1[mi][ni];
            f32x4 v2 = acc2[mi][ni];
            for (int r = 0; r < 4; ++r) {
                size_t idx = (size_t)(mbase + r) * N + n;
                if (EPI == 0) {
                    out1[idx] = (bf16_t)v1[r];
                    out2[idx] = (bf16_t)v2[r];
                } else {
                    float g = v1[r];
                    float sg = g / (1.0f + __expf(-g));
                    out1[idx] = (bf16_t)(sg * v2[r]);
                }
            }
        }
    }
}

// ---------------- Flash attention v2 (causal), KVBLK=64, V pre-transposed ----------------
__global__ __launch_bounds__(256, 3) void attn_k(const bf16_t* __restrict__ qb,
                                                 const bf16_t* __restrict__ kb,
                                                 const bf16_t* __restrict__ vtb,
                                                 bf16_t* __restrict__ ab) {
    __shared__ __align__(16) bf16_t ldsK[64 * 128];   // [k][d], 16B slots src-swizzled
    __shared__ __align__(16) bf16_t ldsVt[128 * 64];  // [d][k], 16B slots src-swizzled
    __shared__ __align__(16) float pbuf[4][16][68];   // per wave: [q][k 0..63] 4-col swizzled
    int bid = blockIdx.x;
    int band = 31 - (bid >> 5);      // heavy bands dispatched first
    int bh = bid & 31;
    int b = bh >> 4, h = bh & 15;
    int q0 = band * 64;
    int tid = threadIdx.x, lane = tid & 63, w = tid >> 6;
    int lr = lane & 15, lg = lane >> 4;
    size_t kqbase = ((size_t)b * SS) * DD + h * HDIM;
    size_t vtbase = ((size_t)(b * HH + h)) * HDIM * SS;
    int qw = q0 + w * 16;

    bf16x8 aq[4];
    #pragma unroll
    for (int kd = 0; kd < 4; ++kd)
        aq[kd] = *(const bf16x8*)(qb + kqbase + (size_t)(qw + lr) * DD + kd * 32 + lg * 8);

    f32x4 acc[8] = {};
    float mrun[4], lrun[4];
    #pragma unroll
    for (int r = 0; r < 4; ++r) { mrun[r] = -1e30f; lrun[r] = 0.f; }
    const float scale = 0.08838834764831845f;  // 1/sqrt(128)

    for (int t = 0; t <= band; ++t) {
        int kk0 = t * 64;
        #pragma unroll
        for (int it = 0; it < 4; ++it) {
            int cid = it * 256 + tid;
            int kr = cid >> 4, kslot = cid & 15;
            gload_lds16(kb + kqbase + (size_t)(kk0 + kr) * DD + ((kslot ^ (kr & 7)) * 8),
                        ldsK + it * 2048 + w * 512);
            int vd = cid >> 3, vslot = cid & 7;
            gload_lds16(vtb + vtbase + (size_t)vd * SS + kk0 + ((vslot ^ (vd & 7)) * 8),
                        ldsVt + it * 2048 + w * 512);
        }
        asm volatile("s_waitcnt vmcnt(0)" ::: "memory");
        __syncthreads();

        // QK^T: S[q 16][k 64]
        f32x4 sf[4];
        #pragma unroll
        for (int nf = 0; nf < 4; ++nf) {
            f32x4 d = {};
            int row = nf * 16 + lr;
            #pragma unroll
            for (int kd = 0; kd < 4; ++kd) {
                bf16x8 bk = *(const bf16x8*)(ldsK + row * 128 +
                                             (((kd * 4 + lg) ^ (lr & 7)) * 8));
                d = __builtin_amdgcn_mfma_f32_16x16x32_bf16(aq[kd], bk, d, 0, 0, 0);
            }
            sf[nf] = d;
        }
        float corr[4];
        #pragma unroll
        for (int r = 0; r < 4; ++r) {
            int qg = qw + lg * 4 + r;
            float s[4];
            #pragma unroll
            for (int nf = 0; nf < 4; ++nf) {
                s[nf] = sf[nf][r] * scale;
                if (kk0 + nf * 16 + lr > qg) s[nf] = -1e30f;
            }
            float mx = fmaxf(fmaxf(s[0], s[1]), fmaxf(s[2], s[3]));
            mx = fmaxf(mx, __shfl_xor(mx, 1));
            mx = fmaxf(mx, __shfl_xor(mx, 2));
            mx = fmaxf(mx, __shfl_xor(mx, 4));
            mx = fmaxf(mx, __shfl_xor(mx, 8));
            float mnew = fmaxf(mrun[r], mx);
            float rs = 0.f;
            #pragma unroll
            for (int nf = 0; nf < 4; ++nf) {
                float p = __expf(s[nf] - mnew);
                rs += p;
                pbuf[w][lg * 4 + r][nf * 16 + (lr ^ (r << 2))] = p;
            }
            rs += __shfl_xor(rs, 1); rs += __shfl_xor(rs, 2);
            rs += __shfl_xor(rs, 4); rs += __shfl_xor(rs, 8);
            corr[r] = __expf(mrun[r] - mnew);
            lrun[r] = lrun[r] * corr[r] + rs;
            mrun[r] = mnew;
        }
        #pragma unroll
        for (int df = 0; df < 8; ++df)
            #pragma unroll
            for (int r = 0; r < 4; ++r) acc[df][r] *= corr[r];
        asm volatile("s_waitcnt lgkmcnt(0)" ::: "memory");
        // PV: two K=32 steps; A-frag rebuilt from pbuf (wave-local)
        #pragma unroll
        for (int ks2 = 0; ks2 < 2; ++ks2) {
            int nfA = ks2 * 2 + (lg >> 1);
            int off = (lg & 1) * 8;
            int sw = (lr & 3) << 2;
            float4 a0 = *(const float4*)&pbuf[w][lr][nfA * 16 + (off ^ sw)];
            float4 a1 = *(const float4*)&pbuf[w][lr][nfA * 16 + ((off + 4) ^ sw)];
            bf16x8 ap;
            ap[0] = (bf16_t)a0.x; ap[1] = (bf16_t)a0.y;
            ap[2] = (bf16_t)a0.z; ap[3] = (bf16_t)a0.w;
            ap[4] = (bf16_t)a1.x; ap[5] = (bf16_t)a1.y;
            ap[6] = (bf16_t)a1.z; ap[7] = (bf16_t)a1.w;
            #pragma unroll
            for (int df = 0; df < 8; ++df) {
                bf16x8 bv = *(const bf16x8*)(ldsVt + (df * 16 + lr) * 64 +
                                             (((ks2 * 4 + lg) ^ (lr & 7)) * 8));
                acc[df] = __builtin_amdgcn_mfma_f32_16x16x32_bf16(ap, bv, acc[df], 0, 0, 0);
            }
        }
        __syncthreads();
    }
    #pragma unroll
    for (int df = 0; df < 8; ++df)
        #pragma unroll
        for (int r = 0; r < 4; ++r) {
            int qg = qw + lg * 4 + r;
            ab[kqbase + (size_t)qg * DD + df * 16 + lr] = (bf16_t)(acc[df][r] / lrun[r]);
        }
}

extern "C" void kernel_launch(void* const* d_in, const int* in_sizes, int n_in,
                              void* d_out, int out_size, void* d_ws, size_t ws_size,
                              hipStream_t stream) {
    const float* hs  = (const float*)d_in[0];
    // d_in[1] = attention_mask (exactly causal) — applied analytically
    const float* Wq  = (const float*)d_in[2];
    const float* Wk  = (const float*)d_in[3];
    const float* Wv  = (const float*)d_in[4];
    const float* Wo  = (const float*)d_in[5];
    const float* Wg  = (const float*)d_in[6];
    const float* Wu  = (const float*)d_in[7];
    const float* Wd  = (const float*)d_in[8];
    const float* ln1 = (const float*)d_in[9];
    const float* ln2 = (const float*)d_in[10];

    char* ws = (char*)d_ws;
    const size_t MB = 1u << 20;
    bf16_t* xb     = (bf16_t*)(ws);                 // 16 MiB [M][D]
    bf16_t* qb     = (bf16_t*)(ws + 16 * MB);       // 16 MiB
    bf16_t* kb     = (bf16_t*)(ws + 32 * MB);       // 16 MiB
    bf16_t* vb     = (bf16_t*)(ws + 48 * MB);       // 16 MiB
    bf16_t* vtb    = (bf16_t*)(ws + 64 * MB);       // 16 MiB (dead before hidden is written)
    float*  cosb   = (float*)(ws + 80 * MB);        // 1 MiB (dead before hidden is written)
    float*  sinb   = (float*)(ws + 81 * MB);        // 1 MiB
    float*  hidden = (float*)(ws + 64 * MB);        // 32 MiB f32, written at Wo step
    bf16_t* wtA    = (bf16_t*)(ws + 96 * MB);       // 23.5 MiB transposed-weight scratch A
    bf16_t* wtB    = (bf16_t*)d_out;                // d_out (32 MiB) as scratch B until final gemm
    bf16_t* ab = xb;   // attn out reuses xb
    bf16_t* yb = xb;   // ln2 out reuses xb
    bf16_t* gb = qb;   // h = silu(gate)*up [M][I] = 43 MiB, reuses q/k/v region

    if (ws_size < (size_t)(98 * MB) + (size_t)II * DD * 2) return;

    // 1. LN1
    rmsnorm_k<<<MM, 256, 0, stream>>>(hs, ln1, xb);
    // 2. RoPE tables
    rope_tables_k<<<SS, 128, 0, stream>>>(cosb, sinb);
    // 3-5. Q & K fused (shared A-tile) — dual-B GEMM
    convT_k<<<dim3(DD / 64, DD / 64), 256, 0, stream>>>(Wq, wtA, DD, DD);
    convT_k<<<dim3(DD / 64, DD / 64), 256, 0, stream>>>(Wk, wtB, DD, DD);
    gemm_dual<0><<<dim3(DD / 128, MM / 128), 256, 0, stream>>>(xb, wtA, wtB, qb, kb, MM, DD, DD);
    // 6-7. V projection
    convT_k<<<dim3(DD / 64, DD / 64), 256, 0, stream>>>(Wv, wtA, DD, DD);
    gemm_bt<0><<<dim3(DD / 128, MM / 128), 256, 0, stream>>>(xb, wtA, vb, nullptr, MM, DD, DD);
    // 8. V transpose for attention B-operand staging
    vtrans_k<<<dim3(DD / 64, SS / 64, BB), 256, 0, stream>>>(vb, vtb);
    // 9. RoPE on q,k
    rope_apply_k<<<(MM * HH * 64) / 256, 256, 0, stream>>>(qb, kb, cosb, sinb);
    // 10. attention (v2: 64 q-rows per block, 1024 blocks)
    attn_k<<<1024, 256, 0, stream>>>(qb, kb, vtb, ab);
    // 11-12. Wo + residual -> hidden (f32; overwrites vtb/cos/sin, all dead)
    convT_k<<<dim3(DD / 64, DD / 64), 256, 0, stream>>>(Wo, wtA, DD, DD);
    gemm_bt<1><<<dim3(DD / 128, MM / 128), 256, 0, stream>>>(ab, wtA, hidden, hs, MM, DD, DD);
    // 13. LN2
    rmsnorm_k<<<MM, 256, 0, stream>>>(hidden, ln2, yb);
    // 14-16. gate & up fused (shared A-tile) + silu-mul epilogue -> gb
    convT_k<<<dim3(II / 64, DD / 64), 256, 0, stream>>>(Wg, wtA, DD, II);
    convT_k<<<dim3(II / 64, DD / 64), 256, 0, stream>>>(Wu, wtB, DD, II);
    gemm_dual<1><<<dim3(II / 128, MM / 128), 256, 0, stream>>>(yb, wtA, wtB, gb, nullptr, MM, II, DD);
    // 17-18. out = hidden + h @ Wd (f32; overwrites wtB scratch = d_out, now dead)
    convT_k<<<dim3(DD / 64, II / 64), 256, 0, stream>>>(Wd, wtA, II, DD);
    gemm_bt<1><<<dim3(DD / 128, MM / 128), 256, 0, stream>>>(gb, wtA, (float*)d_out, hidden, MM, DD, II);
}

// Round 16
// 611.173 us; speedup vs baseline: 1.0998x; 1.0016x over previous
//
#include <hip/hip_runtime.h>
#include <hip/hip_bf16.h>
#include <cmath>

typedef __bf16 bf16_t;
typedef __bf16 bf16x8 __attribute__((ext_vector_type(8)));
typedef float f32x4 __attribute__((ext_vector_type(4)));
typedef unsigned short ushort8 __attribute__((ext_vector_type(8)));

#define DEV __device__ __forceinline__

static constexpr int BB = 2, SS = 2048, DD = 2048, HH = 16, HDIM = 128, II = 5504;
static constexpr int MM = BB * SS; // 4096

DEV void gload_lds16(const void* g, void* l) {
    __builtin_amdgcn_global_load_lds(
        (__attribute__((address_space(1))) void*)const_cast<void*>(g),
        (__attribute__((address_space(3))) void*)l, 16, 0, 0);
}

// ---------------- RMSNorm: f32 in -> bf16 out ----------------
__global__ __launch_bounds__(256) void rmsnorm_k(const float* __restrict__ x,
                                                 const float* __restrict__ w,
                                                 bf16_t* __restrict__ out) {
    int row = blockIdx.x;
    int t = threadIdx.x;
    const float4* xr = (const float4*)(x + (size_t)row * DD);
    float4 a = xr[t];
    float4 b = xr[t + 256];
    float ss = a.x * a.x + a.y * a.y + a.z * a.z + a.w * a.w +
               b.x * b.x + b.y * b.y + b.z * b.z + b.w * b.w;
    for (int m = 1; m < 64; m <<= 1) ss += __shfl_xor(ss, m);
    __shared__ float red[4];
    int lane = t & 63, wv = t >> 6;
    if (lane == 0) red[wv] = ss;
    __syncthreads();
    float scale = rsqrtf((red[0] + red[1] + red[2] + red[3]) * (1.0f / DD) + 1e-6f);
    const float4* w4 = (const float4*)w;
    float4 wa = w4[t], wb = w4[t + 256];
    bf16_t* o = out + (size_t)row * DD;
    union { bf16_t h[4]; ushort4 u; } pa, pb;
    pa.h[0] = (bf16_t)(a.x * scale * wa.x); pa.h[1] = (bf16_t)(a.y * scale * wa.y);
    pa.h[2] = (bf16_t)(a.z * scale * wa.z); pa.h[3] = (bf16_t)(a.w * scale * wa.w);
    pb.h[0] = (bf16_t)(b.x * scale * wb.x); pb.h[1] = (bf16_t)(b.y * scale * wb.y);
    pb.h[2] = (bf16_t)(b.z * scale * wb.z); pb.h[3] = (bf16_t)(b.w * scale * wb.w);
    ((ushort4*)o)[t] = pa.u;
    ((ushort4*)o)[t + 256] = pb.u;
}

// ---------------- RoPE tables ----------------
__global__ void rope_tables_k(float* __restrict__ cosb, float* __restrict__ sinb) {
    int s = blockIdx.x;
    int d = threadIdx.x;       // 0..127
    int j = d & 63;
    float inv = powf(10000.0f, -(2.0f * (float)j) / 128.0f);
    float ang = (float)s * inv;
    cosb[s * HDIM + d] = cosf(ang);
    sinb[s * HDIM + d] = sinf(ang);
}

// ---------------- RoPE apply (in-place on q and k, bf16) ----------------
__global__ __launch_bounds__(256) void rope_apply_k(bf16_t* __restrict__ q,
                                                    bf16_t* __restrict__ k,
                                                    const float* __restrict__ cosb,
                                                    const float* __restrict__ sinb) {
    int t = blockIdx.x * 256 + threadIdx.x;   // [0, M*H*64)
    int j = t & 63;
    int h = (t >> 6) & 15;
    int m = t >> 10;          // 0..4095
    int s = m & (SS - 1);
    size_t idx = (size_t)m * DD + h * HDIM + j;
    float c = cosb[s * HDIM + j];
    float sn = sinb[s * HDIM + j];
    float q1 = (float)q[idx], q2 = (float)q[idx + 64];
    q[idx]      = (bf16_t)(q1 * c - q2 * sn);
    q[idx + 64] = (bf16_t)(q2 * c + q1 * sn);
    float k1 = (float)k[idx], k2 = (float)k[idx + 64];
    k[idx]      = (bf16_t)(k1 * c - k2 * sn);
    k[idx + 64] = (bf16_t)(k2 * c + k1 * sn);
}

// ---------------- convT v2: W[K][N] f32 -> Wt[N][K] bf16, 64x64 tile, vectorized ----------------
__global__ __launch_bounds__(256) void convT_k(const float* __restrict__ W,
                                               bf16_t* __restrict__ Wt,
                                               int K, int N) {
    __shared__ float tile[64][65];
    int n0 = blockIdx.x * 64, k0 = blockIdx.y * 64;
    int t = threadIdx.x;
    int r = t >> 4, cq = t & 15;
    #pragma unroll
    for (int it = 0; it < 4; ++it) {
        int row = it * 16 + r;
        float4 v = *(const float4*)(W + (size_t)(k0 + row) * N + n0 + cq * 4);
        tile[row][cq * 4 + 0] = v.x;
        tile[row][cq * 4 + 1] = v.y;
        tile[row][cq * 4 + 2] = v.z;
        tile[row][cq * 4 + 3] = v.w;
    }
    __syncthreads();
    int n = t >> 2, kq = t & 3;
    #pragma unroll
    for (int it = 0; it < 2; ++it) {
        int k = (it * 4 + kq) * 8;
        union { bf16_t h[8]; ushort8 u; } p;
        #pragma unroll
        for (int j = 0; j < 8; ++j) p.h[j] = (bf16_t)tile[k + j][n];
        *(ushort8*)(Wt + (size_t)(n0 + n) * K + k0 + k) = p.u;
    }
}

// ---------------- V transpose v2: vb[b][s][c] -> vtb[b][c][s], 64x64, ushort8 both ways ----------------
__global__ __launch_bounds__(256) void vtrans_k(const bf16_t* __restrict__ vbp,
                                                bf16_t* __restrict__ vtb) {
    __shared__ ushort tile[64][70];
    int b = blockIdx.z;
    int c0 = blockIdx.x * 64, s0 = blockIdx.y * 64;
    int t = threadIdx.x;
    const ushort* in = (const ushort*)vbp + (size_t)b * SS * DD;
    ushort* out = (ushort*)vtb + (size_t)b * DD * SS;
    int s = t >> 3, coct = t & 7;
    #pragma unroll
    for (int it = 0; it < 2; ++it) {
        int srow = it * 32 + s;
        ushort8 v = *(const ushort8*)(in + (size_t)(s0 + srow) * DD + c0 + coct * 8);
        #pragma unroll
        for (int j = 0; j < 8; ++j) tile[srow][coct * 8 + j] = v[j];
    }
    __syncthreads();
    int c = t >> 3, soct = t & 7;
    #pragma unroll
    for (int it = 0; it < 2; ++it) {
        int ccol = it * 32 + c;
        ushort8 v;
        #pragma unroll
        for (int j = 0; j < 8; ++j) v[j] = tile[soct * 8 + j][ccol];
        *(ushort8*)(out + (size_t)(c0 + ccol) * SS + s0 + soct * 8) = v;
    }
}

// ---------------- GEMM (r5-proven): C[M][N] = A[M][K] * Bt[N][K]^T ----------------
// EPI 0: bf16 store. EPI 1: f32 store = res + acc.
template <int EPI>
__global__ __launch_bounds__(256, 2) void gemm_bt(const bf16_t* __restrict__ A,
                                                  const bf16_t* __restrict__ Bt,
                                                  void* __restrict__ outp,
                                                  const float* __restrict__ res,
                                                  int M, int N, int K) {
    __shared__ __align__(16) bf16_t ldsA[128 * 64];
    __shared__ __align__(16) bf16_t ldsB[128 * 64];
    int tid = threadIdx.x, lane = tid & 63, w = tid >> 6;
    int lr = lane & 15, lg = lane >> 4;

    int GX = gridDim.x, GYd = gridDim.y;
    int bid = blockIdx.y * GX + blockIdx.x;
    int nwg = GX * GYd;
    int qc = nwg >> 3, rc = nwg & 7;
    int xcd = bid & 7, jj = bid >> 3;
    int wg = (xcd < rc ? xcd * (qc + 1) : rc * (qc + 1) + (xcd - rc) * qc) + jj;
    int bx = wg / GYd;
    int by = wg % GYd;

    int m0 = by * 128, n0 = bx * 128;
    int wr = w >> 1, wc = w & 1;
    f32x4 acc[4][4] = {};
    int srow = w * 8 + (lane >> 3);  // 0..31
    int sslot = lane & 7;

    for (int kt = 0; kt < K; kt += 64) {
        for (int i = 0; i < 4; ++i) {
            int row = i * 32 + srow;
            int sp = sslot ^ (row & 7);
            gload_lds16(A + (size_t)(m0 + row) * K + kt + sp * 8,
                        ldsA + i * 2048 + w * 512);
            gload_lds16(Bt + (size_t)(n0 + row) * K + kt + sp * 8,
                        ldsB + i * 2048 + w * 512);
        }
        asm volatile("s_waitcnt vmcnt(0)" ::: "memory");
        __syncthreads();
        for (int kk = 0; kk < 2; ++kk) {
            bf16x8 af[4], bfm[4];
            for (int x = 0; x < 4; ++x) {
                int ra = wr * 64 + x * 16 + lr;
                int sa = (kk * 4 + lg) ^ (ra & 7);
                af[x] = *(const bf16x8*)(ldsA + ra * 64 + sa * 8);
                int rb = wc * 64 + x * 16 + lr;
                int sb = (kk * 4 + lg) ^ (rb & 7);
                bfm[x] = *(const bf16x8*)(ldsB + rb * 64 + sb * 8);
            }
            for (int mi = 0; mi < 4; ++mi)
                for (int ni = 0; ni < 4; ++ni)
                    acc[mi][ni] = __builtin_amdgcn_mfma_f32_16x16x32_bf16(
                        af[mi], bfm[ni], acc[mi][ni], 0, 0, 0);
        }
        __syncthreads();
    }

    for (int mi = 0; mi < 4; ++mi) {
        int mbase = m0 + wr * 64 + mi * 16 + lg * 4;
        for (int ni = 0; ni < 4; ++ni) {
            int n = n0 + wc * 64 + ni * 16 + lr;
            f32x4 v = acc[mi][ni];
            for (int r = 0; r < 4; ++r) {
                size_t idx = (size_t)(mbase + r) * N + n;
                if (EPI == 0) ((bf16_t*)outp)[idx] = (bf16_t)v[r];
                else          ((float*)outp)[idx] = res[idx] + v[r];
            }
        }
    }
}

// ---------------- Dual-B GEMM: one A-tile, two B-panels, two accumulators ----------------
// EPI 0 (QK): out1=bf16(acc1), out2=bf16(acc2).
// EPI 1 (gate/up): out1 = bf16( silu(acc1) * acc2 ).
template <int EPI>
__global__ __launch_bounds__(256, 2) void gemm_dual(const bf16_t* __restrict__ A,
                                                    const bf16_t* __restrict__ B1,
                                                    const bf16_t* __restrict__ B2,
                                                    bf16_t* __restrict__ out1,
                                                    bf16_t* __restrict__ out2,
                                                    int M, int N, int K) {
    __shared__ __align__(16) bf16_t ldsA[128 * 64];
    __shared__ __align__(16) bf16_t ldsB1[128 * 64];
    __shared__ __align__(16) bf16_t ldsB2[128 * 64];
    int tid = threadIdx.x, lane = tid & 63, w = tid >> 6;
    int lr = lane & 15, lg = lane >> 4;

    int GX = gridDim.x, GYd = gridDim.y;
    int bid = blockIdx.y * GX + blockIdx.x;
    int nwg = GX * GYd;
    int qc = nwg >> 3, rc = nwg & 7;
    int xcd = bid & 7, jj = bid >> 3;
    int wg = (xcd < rc ? xcd * (qc + 1) : rc * (qc + 1) + (xcd - rc) * qc) + jj;
    int bx = wg / GYd;
    int by = wg % GYd;

    int m0 = by * 128, n0 = bx * 128;
    int wr = w >> 1, wc = w & 1;
    f32x4 acc1[4][4] = {};
    f32x4 acc2[4][4] = {};
    int srow = w * 8 + (lane >> 3);  // 0..31
    int sslot = lane & 7;

    for (int kt = 0; kt < K; kt += 64) {
        for (int i = 0; i < 4; ++i) {
            int row = i * 32 + srow;
            int sp = sslot ^ (row & 7);
            gload_lds16(A  + (size_t)(m0 + row) * K + kt + sp * 8, ldsA  + i * 2048 + w * 512);
            gload_lds16(B1 + (size_t)(n0 + row) * K + kt + sp * 8, ldsB1 + i * 2048 + w * 512);
            gload_lds16(B2 + (size_t)(n0 + row) * K + kt + sp * 8, ldsB2 + i * 2048 + w * 512);
        }
        asm volatile("s_waitcnt vmcnt(0)" ::: "memory");
        __syncthreads();
        for (int kk = 0; kk < 2; ++kk) {
            bf16x8 af[4], bfm[4];
            for (int x = 0; x < 4; ++x) {
                int ra = wr * 64 + x * 16 + lr;
                af[x] = *(const bf16x8*)(ldsA + ra * 64 + (((kk * 4 + lg) ^ (ra & 7)) * 8));
            }
            for (int x = 0; x < 4; ++x) {
                int rb = wc * 64 + x * 16 + lr;
                bfm[x] = *(const bf16x8*)(ldsB1 + rb * 64 + (((kk * 4 + lg) ^ (rb & 7)) * 8));
            }
            for (int mi = 0; mi < 4; ++mi)
                for (int ni = 0; ni < 4; ++ni)
                    acc1[mi][ni] = __builtin_amdgcn_mfma_f32_16x16x32_bf16(
                        af[mi], bfm[ni], acc1[mi][ni], 0, 0, 0);
            for (int x = 0; x < 4; ++x) {
                int rb = wc * 64 + x * 16 + lr;
                bfm[x] = *(const bf16x8*)(ldsB2 + rb * 64 + (((kk * 4 + lg) ^ (rb & 7)) * 8));
            }
            for (int mi = 0; mi < 4; ++mi)
                for (int ni = 0; ni < 4; ++ni)
                    acc2[mi][ni] = __builtin_amdgcn_mfma_f32_16x16x32_bf16(
                        af[mi], bfm[ni], acc2[mi][ni], 0, 0, 0);
        }
        __syncthreads();
    }

    for (int mi = 0; mi < 4; ++mi) {
        int mbase = m0 + wr * 64 + mi * 16 + lg * 4;
        for (int ni = 0; ni < 4; ++ni) {
            int n = n0 + wc * 64 + ni * 16 + lr;
            f32x4 v1 = acc1[mi][ni];
            f32x4 v2 = acc2[mi][ni];
            for (int r = 0; r < 4; ++r) {
                size_t idx = (size_t)(mbase + r) * N + n;
                if (EPI == 0) {
                    out1[idx] = (bf16_t)v1[r];
                    out2[idx] = (bf16_t)v2[r];
                } else {
                    float g = v1[r];
                    float sg = g / (1.0f + __expf(-g));
                    out1[idx] = (bf16_t)(sg * v2[r]);
                }
            }
        }
    }
}

// ---------------- Flash attention v2 + T13 defer-max (causal), KVBLK=64 ----------------
__global__ __launch_bounds__(256, 3) void attn_k(const bf16_t* __restrict__ qb,
                                                 const bf16_t* __restrict__ kb,
                                                 const bf16_t* __restrict__ vtb,
                                                 bf16_t* __restrict__ ab) {
    __shared__ __align__(16) bf16_t ldsK[64 * 128];   // [k][d], 16B slots src-swizzled
    __shared__ __align__(16) bf16_t ldsVt[128 * 64];  // [d][k], 16B slots src-swizzled
    __shared__ __align__(16) float pbuf[4][16][68];   // per wave: [q][k 0..63] 4-col swizzled
    int bid = blockIdx.x;
    int band = 31 - (bid >> 5);      // heavy bands dispatched first
    int bh = bid & 31;
    int b = bh >> 4, h = bh & 15;
    int q0 = band * 64;
    int tid = threadIdx.x, lane = tid & 63, w = tid >> 6;
    int lr = lane & 15, lg = lane >> 4;
    size_t kqbase = ((size_t)b * SS) * DD + h * HDIM;
    size_t vtbase = ((size_t)(b * HH + h)) * HDIM * SS;
    int qw = q0 + w * 16;

    bf16x8 aq[4];
    #pragma unroll
    for (int kd = 0; kd < 4; ++kd)
        aq[kd] = *(const bf16x8*)(qb + kqbase + (size_t)(qw + lr) * DD + kd * 32 + lg * 8);

    f32x4 acc[8] = {};
    float mrun[4], lrun[4];
    #pragma unroll
    for (int r = 0; r < 4; ++r) { mrun[r] = -1e30f; lrun[r] = 0.f; }
    const float scale = 0.08838834764831845f;  // 1/sqrt(128)

    for (int t = 0; t <= band; ++t) {
        int kk0 = t * 64;
        #pragma unroll
        for (int it = 0; it < 4; ++it) {
            int cid = it * 256 + tid;
            int kr = cid >> 4, kslot = cid & 15;
            gload_lds16(kb + kqbase + (size_t)(kk0 + kr) * DD + ((kslot ^ (kr & 7)) * 8),
                        ldsK + it * 2048 + w * 512);
            int vd = cid >> 3, vslot = cid & 7;
            gload_lds16(vtb + vtbase + (size_t)vd * SS + kk0 + ((vslot ^ (vd & 7)) * 8),
                        ldsVt + it * 2048 + w * 512);
        }
        asm volatile("s_waitcnt vmcnt(0)" ::: "memory");
        __syncthreads();

        // QK^T: S[q 16][k 64]
        f32x4 sf[4];
        #pragma unroll
        for (int nf = 0; nf < 4; ++nf) {
            f32x4 d = {};
            int row = nf * 16 + lr;
            #pragma unroll
            for (int kd = 0; kd < 4; ++kd) {
                bf16x8 bk = *(const bf16x8*)(ldsK + row * 128 +
                                             (((kd * 4 + lg) ^ (lr & 7)) * 8));
                d = __builtin_amdgcn_mfma_f32_16x16x32_bf16(aq[kd], bk, d, 0, 0, 0);
            }
            sf[nf] = d;
        }
        // per-row masked max
        float mx[4], dmax = -1e30f;
        #pragma unroll
        for (int r = 0; r < 4; ++r) {
            int qg = qw + lg * 4 + r;
            float m2 = -1e30f;
            #pragma unroll
            for (int nf = 0; nf < 4; ++nf) {
                float sv = sf[nf][r] * scale;
                if (kk0 + nf * 16 + lr > qg) sv = -1e30f;
                m2 = fmaxf(m2, sv);
            }
            m2 = fmaxf(m2, __shfl_xor(m2, 1));
            m2 = fmaxf(m2, __shfl_xor(m2, 2));
            m2 = fmaxf(m2, __shfl_xor(m2, 4));
            m2 = fmaxf(m2, __shfl_xor(m2, 8));
            mx[r] = m2;
            dmax = fmaxf(dmax, m2 - mrun[r]);
        }
        // T13: O-rescale only when some row's max grew past the threshold (rare)
        if (!__all(dmax <= 8.0f)) {
            #pragma unroll
            for (int r = 0; r < 4; ++r) {
                float mnew = fmaxf(mrun[r], mx[r]);
                float corr = __expf(mrun[r] - mnew);
                lrun[r] *= corr;
                mrun[r] = mnew;
                #pragma unroll
                for (int df = 0; df < 8; ++df) acc[df][r] *= corr;
            }
        }
        #pragma unroll
        for (int r = 0; r < 4; ++r) {
            int qg = qw + lg * 4 + r;
            float rs = 0.f;
            #pragma unroll
            for (int nf = 0; nf < 4; ++nf) {
                float sv = sf[nf][r] * scale;
                if (kk0 + nf * 16 + lr > qg) sv = -1e30f;
                float p = __expf(sv - mrun[r]);
                rs += p;
                pbuf[w][lg * 4 + r][nf * 16 + (lr ^ (r << 2))] = p;
            }
            rs += __shfl_xor(rs, 1); rs += __shfl_xor(rs, 2);
            rs += __shfl_xor(rs, 4); rs += __shfl_xor(rs, 8);
            lrun[r] += rs;
        }
        asm volatile("s_waitcnt lgkmcnt(0)" ::: "memory");
        // PV: two K=32 steps; A-frag rebuilt from pbuf (wave-local)
        #pragma unroll
        for (int ks2 = 0; ks2 < 2; ++ks2) {
            int nfA = ks2 * 2 + (lg >> 1);
            int off = (lg & 1) * 8;
            int sw = (lr & 3) << 2;
            float4 a0 = *(const float4*)&pbuf[w][lr][nfA * 16 + (off ^ sw)];
            float4 a1 = *(const float4*)&pbuf[w][lr][nfA * 16 + ((off + 4) ^ sw)];
            bf16x8 ap;
            ap[0] = (bf16_t)a0.x; ap[1] = (bf16_t)a0.y;
            ap[2] = (bf16_t)a0.z; ap[3] = (bf16_t)a0.w;
            ap[4] = (bf16_t)a1.x; ap[5] = (bf16_t)a1.y;
            ap[6] = (bf16_t)a1.z; ap[7] = (bf16_t)a1.w;
            #pragma unroll
            for (int df = 0; df < 8; ++df) {
                bf16x8 bv = *(const bf16x8*)(ldsVt + (df * 16 + lr) * 64 +
                                             (((ks2 * 4 + lg) ^ (lr & 7)) * 8));
                acc[df] = __builtin_amdgcn_mfma_f32_16x16x32_bf16(ap, bv, acc[df], 0, 0, 0);
            }
        }
        __syncthreads();
    }
    #pragma unroll
    for (int df = 0; df < 8; ++df)
        #pragma unroll
        for (int r = 0; r < 4; ++r) {
            int qg = qw + lg * 4 + r;
            ab[kqbase + (size_t)qg * DD + df * 16 + lr] = (bf16_t)(acc[df][r] / lrun[r]);
        }
}

extern "C" void kernel_launch(void* const* d_in, const int* in_sizes, int n_in,
                              void* d_out, int out_size, void* d_ws, size_t ws_size,
                              hipStream_t stream) {
    const float* hs  = (const float*)d_in[0];
    // d_in[1] = attention_mask (exactly causal) — applied analytically
    const float* Wq  = (const float*)d_in[2];
    const float* Wk  = (const float*)d_in[3];
    const float* Wv  = (const float*)d_in[4];
    const float* Wo  = (const float*)d_in[5];
    const float* Wg  = (const float*)d_in[6];
    const float* Wu  = (const float*)d_in[7];
    const float* Wd  = (const float*)d_in[8];
    const float* ln1 = (const float*)d_in[9];
    const float* ln2 = (const float*)d_in[10];

    char* ws = (char*)d_ws;
    const size_t MB = 1u << 20;
    bf16_t* xb     = (bf16_t*)(ws);                 // 16 MiB [M][D]
    bf16_t* qb     = (bf16_t*)(ws + 16 * MB);       // 16 MiB
    bf16_t* kb     = (bf16_t*)(ws + 32 * MB);       // 16 MiB
    bf16_t* vb     = (bf16_t*)(ws + 48 * MB);       // 16 MiB
    bf16_t* vtb    = (bf16_t*)(ws + 64 * MB);       // 16 MiB (dead before hidden is written)
    float*  cosb   = (float*)(ws + 80 * MB);        // 1 MiB (dead before hidden is written)
    float*  sinb   = (float*)(ws + 81 * MB);        // 1 MiB
    float*  hidden = (float*)(ws + 64 * MB);        // 32 MiB f32, written at Wo step
    bf16_t* wtA    = (bf16_t*)(ws + 96 * MB);       // 23.5 MiB transposed-weight scratch A
    bf16_t* wtB    = (bf16_t*)d_out;                // d_out (32 MiB) as scratch B until final gemm
    bf16_t* ab = xb;   // attn out reuses xb
    bf16_t* yb = xb;   // ln2 out reuses xb
    bf16_t* gb = qb;   // h = silu(gate)*up [M][I] = 43 MiB, reuses q/k/v region

    if (ws_size < (size_t)(98 * MB) + (size_t)II * DD * 2) return;

    // 1. LN1
    rmsnorm_k<<<MM, 256, 0, stream>>>(hs, ln1, xb);
    // 2. RoPE tables
    rope_tables_k<<<SS, 128, 0, stream>>>(cosb, sinb);
    // 3-5. Q & K fused (shared A-tile) — dual-B GEMM
    convT_k<<<dim3(DD / 64, DD / 64), 256, 0, stream>>>(Wq, wtA, DD, DD);
    convT_k<<<dim3(DD / 64, DD / 64), 256, 0, stream>>>(Wk, wtB, DD, DD);
    gemm_dual<0><<<dim3(DD / 128, MM / 128), 256, 0, stream>>>(xb, wtA, wtB, qb, kb, MM, DD, DD);
    // 6-7. V projection
    convT_k<<<dim3(DD / 64, DD / 64), 256, 0, stream>>>(Wv, wtA, DD, DD);
    gemm_bt<0><<<dim3(DD / 128, MM / 128), 256, 0, stream>>>(xb, wtA, vb, nullptr, MM, DD, DD);
    // 8. V transpose for attention B-operand staging
    vtrans_k<<<dim3(DD / 64, SS / 64, BB), 256, 0, stream>>>(vb, vtb);
    // 9. RoPE on q,k
    rope_apply_k<<<(MM * HH * 64) / 256, 256, 0, stream>>>(qb, kb, cosb, sinb);
    // 10. attention (v2 + T13)
    attn_k<<<1024, 256, 0, stream>>>(qb, kb, vtb, ab);
    // 11-12. Wo + residual -> hidden (f32; overwrites vtb/cos/sin, all dead)
    convT_k<<<dim3(DD / 64, DD / 64), 256, 0, stream>>>(Wo, wtA, DD, DD);
    gemm_bt<1><<<dim3(DD / 128, MM / 128), 256, 0, stream>>>(ab, wtA, hidden, hs, MM, DD, DD);
    // 13. LN2
    rmsnorm_k<<<MM, 256, 0, stream>>>(hidden, ln2, yb);
    // 14-16. gate & up fused (shared A-tile) + silu-mul epilogue -> gb
    convT_k<<<dim3(II / 64, DD / 64), 256, 0, stream>>>(Wg, wtA, DD, II);
    convT_k<<<dim3(II / 64, DD / 64), 256, 0, stream>>>(Wu, wtB, DD, II);
    gemm_dual<1><<<dim3(II / 128, MM / 128), 256, 0, stream>>>(yb, wtA, wtB, gb, nullptr, MM, II, DD);
    // 17-18. out = hidden + h @ Wd (f32; overwrites wtB scratch = d_out, now dead)
    convT_k<<<dim3(DD / 64, II / 64), 256, 0, stream>>>(Wd, wtA, II, DD);
    gemm_bt<1><<<dim3(DD / 128, MM / 128), 256, 0, stream>>>(gb, wtA, (float*)d_out, hidden, MM, DD, II);
}

// Round 17
// 599.597 us; speedup vs baseline: 1.1210x; 1.0193x over previous
//
#include <hip/hip_runtime.h>
#include <hip/hip_bf16.h>
#include <cmath>

typedef __bf16 bf16_t;
typedef __bf16 bf16x8 __attribute__((ext_vector_type(8)));
typedef float f32x4 __attribute__((ext_vector_type(4)));
typedef unsigned short ushort8 __attribute__((ext_vector_type(8)));

#define DEV __device__ __forceinline__

static constexpr int BB = 2, SS = 2048, DD = 2048, HH = 16, HDIM = 128, II = 5504;
static constexpr int MM = BB * SS; // 4096

DEV void gload_lds16(const void* g, void* l) {
    __builtin_amdgcn_global_load_lds(
        (__attribute__((address_space(1))) void*)const_cast<void*>(g),
        (__attribute__((address_space(3))) void*)l, 16, 0, 0);
}

// ---------------- RMSNorm: f32 in -> bf16 out ----------------
__global__ __launch_bounds__(256) void rmsnorm_k(const float* __restrict__ x,
                                                 const float* __restrict__ w,
                                                 bf16_t* __restrict__ out) {
    int row = blockIdx.x;
    int t = threadIdx.x;
    const float4* xr = (const float4*)(x + (size_t)row * DD);
    float4 a = xr[t];
    float4 b = xr[t + 256];
    float ss = a.x * a.x + a.y * a.y + a.z * a.z + a.w * a.w +
               b.x * b.x + b.y * b.y + b.z * b.z + b.w * b.w;
    for (int m = 1; m < 64; m <<= 1) ss += __shfl_xor(ss, m);
    __shared__ float red[4];
    int lane = t & 63, wv = t >> 6;
    if (lane == 0) red[wv] = ss;
    __syncthreads();
    float scale = rsqrtf((red[0] + red[1] + red[2] + red[3]) * (1.0f / DD) + 1e-6f);
    const float4* w4 = (const float4*)w;
    float4 wa = w4[t], wb = w4[t + 256];
    bf16_t* o = out + (size_t)row * DD;
    union { bf16_t h[4]; ushort4 u; } pa, pb;
    pa.h[0] = (bf16_t)(a.x * scale * wa.x); pa.h[1] = (bf16_t)(a.y * scale * wa.y);
    pa.h[2] = (bf16_t)(a.z * scale * wa.z); pa.h[3] = (bf16_t)(a.w * scale * wa.w);
    pb.h[0] = (bf16_t)(b.x * scale * wb.x); pb.h[1] = (bf16_t)(b.y * scale * wb.y);
    pb.h[2] = (bf16_t)(b.z * scale * wb.z); pb.h[3] = (bf16_t)(b.w * scale * wb.w);
    ((ushort4*)o)[t] = pa.u;
    ((ushort4*)o)[t + 256] = pb.u;
}

// ---------------- RMSNorm: bf16 in -> bf16 out ----------------
__global__ __launch_bounds__(256) void rmsnorm_b(const bf16_t* __restrict__ x,
                                                 const float* __restrict__ w,
                                                 bf16_t* __restrict__ out) {
    int row = blockIdx.x;
    int t = threadIdx.x;
    bf16x8 v = *(const bf16x8*)(x + (size_t)row * DD + t * 8);
    float f[8];
    float ss = 0.f;
    #pragma unroll
    for (int j = 0; j < 8; ++j) { f[j] = (float)v[j]; ss += f[j] * f[j]; }
    for (int m = 1; m < 64; m <<= 1) ss += __shfl_xor(ss, m);
    __shared__ float red[4];
    int lane = t & 63, wv = t >> 6;
    if (lane == 0) red[wv] = ss;
    __syncthreads();
    float scale = rsqrtf((red[0] + red[1] + red[2] + red[3]) * (1.0f / DD) + 1e-6f);
    const float4* w4 = (const float4*)w;
    float4 wa = w4[t * 2], wb = w4[t * 2 + 1];
    bf16x8 o;
    o[0] = (bf16_t)(f[0] * scale * wa.x); o[1] = (bf16_t)(f[1] * scale * wa.y);
    o[2] = (bf16_t)(f[2] * scale * wa.z); o[3] = (bf16_t)(f[3] * scale * wa.w);
    o[4] = (bf16_t)(f[4] * scale * wb.x); o[5] = (bf16_t)(f[5] * scale * wb.y);
    o[6] = (bf16_t)(f[6] * scale * wb.z); o[7] = (bf16_t)(f[7] * scale * wb.w);
    *(bf16x8*)(out + (size_t)row * DD + t * 8) = o;
}

// ---------------- RoPE tables ----------------
__global__ void rope_tables_k(float* __restrict__ cosb, float* __restrict__ sinb) {
    int s = blockIdx.x;
    int d = threadIdx.x;       // 0..127
    int j = d & 63;
    float inv = powf(10000.0f, -(2.0f * (float)j) / 128.0f);
    float ang = (float)s * inv;
    cosb[s * HDIM + d] = cosf(ang);
    sinb[s * HDIM + d] = sinf(ang);
}

// ---------------- RoPE apply (in-place on q and k, bf16) ----------------
__global__ __launch_bounds__(256) void rope_apply_k(bf16_t* __restrict__ q,
                                                    bf16_t* __restrict__ k,
                                                    const float* __restrict__ cosb,
                                                    const float* __restrict__ sinb) {
    int t = blockIdx.x * 256 + threadIdx.x;   // [0, M*H*64)
    int j = t & 63;
    int h = (t >> 6) & 15;
    int m = t >> 10;          // 0..4095
    int s = m & (SS - 1);
    size_t idx = (size_t)m * DD + h * HDIM + j;
    float c = cosb[s * HDIM + j];
    float sn = sinb[s * HDIM + j];
    float q1 = (float)q[idx], q2 = (float)q[idx + 64];
    q[idx]      = (bf16_t)(q1 * c - q2 * sn);
    q[idx + 64] = (bf16_t)(q2 * c + q1 * sn);
    float k1 = (float)k[idx], k2 = (float)k[idx + 64];
    k[idx]      = (bf16_t)(k1 * c - k2 * sn);
    k[idx + 64] = (bf16_t)(k2 * c + k1 * sn);
}

// ---------------- convT v2: W[K][N] f32 -> Wt[N][K] bf16, 64x64 tile, vectorized ----------------
__global__ __launch_bounds__(256) void convT_k(const float* __restrict__ W,
                                               bf16_t* __restrict__ Wt,
                                               int K, int N) {
    __shared__ float tile[64][65];
    int n0 = blockIdx.x * 64, k0 = blockIdx.y * 64;
    int t = threadIdx.x;
    int r = t >> 4, cq = t & 15;
    #pragma unroll
    for (int it = 0; it < 4; ++it) {
        int row = it * 16 + r;
        float4 v = *(const float4*)(W + (size_t)(k0 + row) * N + n0 + cq * 4);
        tile[row][cq * 4 + 0] = v.x;
        tile[row][cq * 4 + 1] = v.y;
        tile[row][cq * 4 + 2] = v.z;
        tile[row][cq * 4 + 3] = v.w;
    }
    __syncthreads();
    int n = t >> 2, kq = t & 3;
    #pragma unroll
    for (int it = 0; it < 2; ++it) {
        int k = (it * 4 + kq) * 8;
        union { bf16_t h[8]; ushort8 u; } p;
        #pragma unroll
        for (int j = 0; j < 8; ++j) p.h[j] = (bf16_t)tile[k + j][n];
        *(ushort8*)(Wt + (size_t)(n0 + n) * K + k0 + k) = p.u;
    }
}

// ---------------- GEMM (r5-proven): C = A[M][K] * Bt[N][K]^T ----------------
// EPI 0: bf16 store. EPI 1: bf16 store = f32res + acc (Wo+residual).
// EPI 2: V transposed store -> vtb[b][n][s]. EPI 3: f32 store = bf16res + acc (down+residual).
template <int EPI>
__global__ __launch_bounds__(256, 2) void gemm_bt(const bf16_t* __restrict__ A,
                                                  const bf16_t* __restrict__ Bt,
                                                  void* __restrict__ outp,
                                                  const void* __restrict__ res,
                                                  int M, int N, int K) {
    __shared__ __align__(16) bf16_t ldsA[128 * 64];
    __shared__ __align__(16) bf16_t ldsB[128 * 64];
    int tid = threadIdx.x, lane = tid & 63, w = tid >> 6;
    int lr = lane & 15, lg = lane >> 4;

    int GX = gridDim.x, GYd = gridDim.y;
    int bid = blockIdx.y * GX + blockIdx.x;
    int nwg = GX * GYd;
    int qc = nwg >> 3, rc = nwg & 7;
    int xcd = bid & 7, jj = bid >> 3;
    int wg = (xcd < rc ? xcd * (qc + 1) : rc * (qc + 1) + (xcd - rc) * qc) + jj;
    int bx = wg / GYd;
    int by = wg % GYd;

    int m0 = by * 128, n0 = bx * 128;
    int wr = w >> 1, wc = w & 1;
    f32x4 acc[4][4] = {};
    int srow = w * 8 + (lane >> 3);  // 0..31
    int sslot = lane & 7;

    for (int kt = 0; kt < K; kt += 64) {
        for (int i = 0; i < 4; ++i) {
            int row = i * 32 + srow;
            int sp = sslot ^ (row & 7);
            gload_lds16(A + (size_t)(m0 + row) * K + kt + sp * 8,
                        ldsA + i * 2048 + w * 512);
            gload_lds16(Bt + (size_t)(n0 + row) * K + kt + sp * 8,
                        ldsB + i * 2048 + w * 512);
        }
        asm volatile("s_waitcnt vmcnt(0)" ::: "memory");
        __syncthreads();
        for (int kk = 0; kk < 2; ++kk) {
            bf16x8 af[4], bfm[4];
            for (int x = 0; x < 4; ++x) {
                int ra = wr * 64 + x * 16 + lr;
                int sa = (kk * 4 + lg) ^ (ra & 7);
                af[x] = *(const bf16x8*)(ldsA + ra * 64 + sa * 8);
                int rb = wc * 64 + x * 16 + lr;
                int sb = (kk * 4 + lg) ^ (rb & 7);
                bfm[x] = *(const bf16x8*)(ldsB + rb * 64 + sb * 8);
            }
            for (int mi = 0; mi < 4; ++mi)
                for (int ni = 0; ni < 4; ++ni)
                    acc[mi][ni] = __builtin_amdgcn_mfma_f32_16x16x32_bf16(
                        af[mi], bfm[ni], acc[mi][ni], 0, 0, 0);
        }
        __syncthreads();
    }

    for (int mi = 0; mi < 4; ++mi) {
        int mbase = m0 + wr * 64 + mi * 16 + lg * 4;
        for (int ni = 0; ni < 4; ++ni) {
            int n = n0 + wc * 64 + ni * 16 + lr;
            f32x4 v = acc[mi][ni];
            if (EPI == 2) {
                // V: write transposed vtb[b][n][s], 4 consecutive s per thread
                int b = mbase >> 11;
                int srw = mbase & (SS - 1);
                union { bf16_t h[4]; ushort4 u; } p;
                p.h[0] = (bf16_t)v[0]; p.h[1] = (bf16_t)v[1];
                p.h[2] = (bf16_t)v[2]; p.h[3] = (bf16_t)v[3];
                *(ushort4*)((bf16_t*)outp + (size_t)b * DD * SS + (size_t)n * SS + srw) = p.u;
            } else {
                for (int r = 0; r < 4; ++r) {
                    size_t idx = (size_t)(mbase + r) * N + n;
                    if (EPI == 0) {
                        ((bf16_t*)outp)[idx] = (bf16_t)v[r];
                    } else if (EPI == 1) {
                        ((bf16_t*)outp)[idx] = (bf16_t)(((const float*)res)[idx] + v[r]);
                    } else {
                        ((float*)outp)[idx] = (float)((const bf16_t*)res)[idx] + v[r];
                    }
                }
            }
        }
    }
}

// ---------------- Dual-B GEMM: one A-tile, two B-panels, two accumulators ----------------
// EPI 0 (QK): out1=bf16(acc1), out2=bf16(acc2).
// EPI 1 (gate/up): out1 = bf16( silu(acc1) * acc2 ).
template <int EPI>
__global__ __launch_bounds__(256, 2) void gemm_dual(const bf16_t* __restrict__ A,
                                                    const bf16_t* __restrict__ B1,
                                                    const bf16_t* __restrict__ B2,
                                                    bf16_t* __restrict__ out1,
                                                    bf16_t* __restrict__ out2,
                                                    int M, int N, int K) {
    __shared__ __align__(16) bf16_t ldsA[128 * 64];
    __shared__ __align__(16) bf16_t ldsB1[128 * 64];
    __shared__ __align__(16) bf16_t ldsB2[128 * 64];
    int tid = threadIdx.x, lane = tid & 63, w = tid >> 6;
    int lr = lane & 15, lg = lane >> 4;

    int GX = gridDim.x, GYd = gridDim.y;
    int bid = blockIdx.y * GX + blockIdx.x;
    int nwg = GX * GYd;
    int qc = nwg >> 3, rc = nwg & 7;
    int xcd = bid & 7, jj = bid >> 3;
    int wg = (xcd < rc ? xcd * (qc + 1) : rc * (qc + 1) + (xcd - rc) * qc) + jj;
    int bx = wg / GYd;
    int by = wg % GYd;

    int m0 = by * 128, n0 = bx * 128;
    int wr = w >> 1, wc = w & 1;
    f32x4 acc1[4][4] = {};
    f32x4 acc2[4][4] = {};
    int srow = w * 8 + (lane >> 3);  // 0..31
    int sslot = lane & 7;

    for (int kt = 0; kt < K; kt += 64) {
        for (int i = 0; i < 4; ++i) {
            int row = i * 32 + srow;
            int sp = sslot ^ (row & 7);
            gload_lds16(A  + (size_t)(m0 + row) * K + kt + sp * 8, ldsA  + i * 2048 + w * 512);
            gload_lds16(B1 + (size_t)(n0 + row) * K + kt + sp * 8, ldsB1 + i * 2048 + w * 512);
            gload_lds16(B2 + (size_t)(n0 + row) * K + kt + sp * 8, ldsB2 + i * 2048 + w * 512);
        }
        asm volatile("s_waitcnt vmcnt(0)" ::: "memory");
        __syncthreads();
        for (int kk = 0; kk < 2; ++kk) {
            bf16x8 af[4], bfm[4];
            for (int x = 0; x < 4; ++x) {
                int ra = wr * 64 + x * 16 + lr;
                af[x] = *(const bf16x8*)(ldsA + ra * 64 + (((kk * 4 + lg) ^ (ra & 7)) * 8));
            }
            for (int x = 0; x < 4; ++x) {
                int rb = wc * 64 + x * 16 + lr;
                bfm[x] = *(const bf16x8*)(ldsB1 + rb * 64 + (((kk * 4 + lg) ^ (rb & 7)) * 8));
            }
            for (int mi = 0; mi < 4; ++mi)
                for (int ni = 0; ni < 4; ++ni)
                    acc1[mi][ni] = __builtin_amdgcn_mfma_f32_16x16x32_bf16(
                        af[mi], bfm[ni], acc1[mi][ni], 0, 0, 0);
            for (int x = 0; x < 4; ++x) {
                int rb = wc * 64 + x * 16 + lr;
                bfm[x] = *(const bf16x8*)(ldsB2 + rb * 64 + (((kk * 4 + lg) ^ (rb & 7)) * 8));
            }
            for (int mi = 0; mi < 4; ++mi)
                for (int ni = 0; ni < 4; ++ni)
                    acc2[mi][ni] = __builtin_amdgcn_mfma_f32_16x16x32_bf16(
                        af[mi], bfm[ni], acc2[mi][ni], 0, 0, 0);
        }
        __syncthreads();
    }

    for (int mi = 0; mi < 4; ++mi) {
        int mbase = m0 + wr * 64 + mi * 16 + lg * 4;
        for (int ni = 0; ni < 4; ++ni) {
            int n = n0 + wc * 64 + ni * 16 + lr;
            f32x4 v1 = acc1[mi][ni];
            f32x4 v2 = acc2[mi][ni];
            for (int r = 0; r < 4; ++r) {
                size_t idx = (size_t)(mbase + r) * N + n;
                if (EPI == 0) {
                    out1[idx] = (bf16_t)v1[r];
                    out2[idx] = (bf16_t)v2[r];
                } else {
                    float g = v1[r];
                    float sg = g / (1.0f + __expf(-g));
                    out1[idx] = (bf16_t)(sg * v2[r]);
                }
            }
        }
    }
}

// ---------------- Flash attention v2 + T13 defer-max (causal), KVBLK=64 ----------------
__global__ __launch_bounds__(256, 3) void attn_k(const bf16_t* __restrict__ qb,
                                                 const bf16_t* __restrict__ kb,
                                                 const bf16_t* __restrict__ vtb,
                                                 bf16_t* __restrict__ ab) {
    __shared__ __align__(16) bf16_t ldsK[64 * 128];   // [k][d], 16B slots src-swizzled
    __shared__ __align__(16) bf16_t ldsVt[128 * 64];  // [d][k], 16B slots src-swizzled
    __shared__ __align__(16) float pbuf[4][16][68];   // per wave: [q][k 0..63] 4-col swizzled
    int bid = blockIdx.x;
    int band = 31 - (bid >> 5);      // heavy bands dispatched first
    int bh = bid & 31;
    int b = bh >> 4, h = bh & 15;
    int q0 = band * 64;
    int tid = threadIdx.x, lane = tid & 63, w = tid >> 6;
    int lr = lane & 15, lg = lane >> 4;
    size_t kqbase = ((size_t)b * SS) * DD + h * HDIM;
    size_t vtbase = ((size_t)(b * HH + h)) * HDIM * SS;
    int qw = q0 + w * 16;

    bf16x8 aq[4];
    #pragma unroll
    for (int kd = 0; kd < 4; ++kd)
        aq[kd] = *(const bf16x8*)(qb + kqbase + (size_t)(qw + lr) * DD + kd * 32 + lg * 8);

    f32x4 acc[8] = {};
    float mrun[4], lrun[4];
    #pragma unroll
    for (int r = 0; r < 4; ++r) { mrun[r] = -1e30f; lrun[r] = 0.f; }
    const float scale = 0.08838834764831845f;  // 1/sqrt(128)

    for (int t = 0; t <= band; ++t) {
        int kk0 = t * 64;
        #pragma unroll
        for (int it = 0; it < 4; ++it) {
            int cid = it * 256 + tid;
            int kr = cid >> 4, kslot = cid & 15;
            gload_lds16(kb + kqbase + (size_t)(kk0 + kr) * DD + ((kslot ^ (kr & 7)) * 8),
                        ldsK + it * 2048 + w * 512);
            int vd = cid >> 3, vslot = cid & 7;
            gload_lds16(vtb + vtbase + (size_t)vd * SS + kk0 + ((vslot ^ (vd & 7)) * 8),
                        ldsVt + it * 2048 + w * 512);
        }
        asm volatile("s_waitcnt vmcnt(0)" ::: "memory");
        __syncthreads();

        // QK^T: S[q 16][k 64]
        f32x4 sf[4];
        #pragma unroll
        for (int nf = 0; nf < 4; ++nf) {
            f32x4 d = {};
            int row = nf * 16 + lr;
            #pragma unroll
            for (int kd = 0; kd < 4; ++kd) {
                bf16x8 bk = *(const bf16x8*)(ldsK + row * 128 +
                                             (((kd * 4 + lg) ^ (lr & 7)) * 8));
                d = __builtin_amdgcn_mfma_f32_16x16x32_bf16(aq[kd], bk, d, 0, 0, 0);
            }
            sf[nf] = d;
        }
        // per-row masked max
        float mx[4], dmax = -1e30f;
        #pragma unroll
        for (int r = 0; r < 4; ++r) {
            int qg = qw + lg * 4 + r;
            float m2 = -1e30f;
            #pragma unroll
            for (int nf = 0; nf < 4; ++nf) {
                float sv = sf[nf][r] * scale;
                if (kk0 + nf * 16 + lr > qg) sv = -1e30f;
                m2 = fmaxf(m2, sv);
            }
            m2 = fmaxf(m2, __shfl_xor(m2, 1));
            m2 = fmaxf(m2, __shfl_xor(m2, 2));
            m2 = fmaxf(m2, __shfl_xor(m2, 4));
            m2 = fmaxf(m2, __shfl_xor(m2, 8));
            mx[r] = m2;
            dmax = fmaxf(dmax, m2 - mrun[r]);
        }
        // T13: O-rescale only when some row's max grew past the threshold (rare)
        if (!__all(dmax <= 8.0f)) {
            #pragma unroll
            for (int r = 0; r < 4; ++r) {
                float mnew = fmaxf(mrun[r], mx[r]);
                float corr = __expf(mrun[r] - mnew);
                lrun[r] *= corr;
                mrun[r] = mnew;
                #pragma unroll
                for (int df = 0; df < 8; ++df) acc[df][r] *= corr;
            }
        }
        #pragma unroll
        for (int r = 0; r < 4; ++r) {
            int qg = qw + lg * 4 + r;
            float rs = 0.f;
            #pragma unroll
            for (int nf = 0; nf < 4; ++nf) {
                float sv = sf[nf][r] * scale;
                if (kk0 + nf * 16 + lr > qg) sv = -1e30f;
                float p = __expf(sv - mrun[r]);
                rs += p;
                pbuf[w][lg * 4 + r][nf * 16 + (lr ^ (r << 2))] = p;
            }
            rs += __shfl_xor(rs, 1); rs += __shfl_xor(rs, 2);
            rs += __shfl_xor(rs, 4); rs += __shfl_xor(rs, 8);
            lrun[r] += rs;
        }
        asm volatile("s_waitcnt lgkmcnt(0)" ::: "memory");
        // PV: two K=32 steps; A-frag rebuilt from pbuf (wave-local)
        #pragma unroll
        for (int ks2 = 0; ks2 < 2; ++ks2) {
            int nfA = ks2 * 2 + (lg >> 1);
            int off = (lg & 1) * 8;
            int sw = (lr & 3) << 2;
            float4 a0 = *(const float4*)&pbuf[w][lr][nfA * 16 + (off ^ sw)];
            float4 a1 = *(const float4*)&pbuf[w][lr][nfA * 16 + ((off + 4) ^ sw)];
            bf16x8 ap;
            ap[0] = (bf16_t)a0.x; ap[1] = (bf16_t)a0.y;
            ap[2] = (bf16_t)a0.z; ap[3] = (bf16_t)a0.w;
            ap[4] = (bf16_t)a1.x; ap[5] = (bf16_t)a1.y;
            ap[6] = (bf16_t)a1.z; ap[7] = (bf16_t)a1.w;
            #pragma unroll
            for (int df = 0; df < 8; ++df) {
                bf16x8 bv = *(const bf16x8*)(ldsVt + (df * 16 + lr) * 64 +
                                             (((ks2 * 4 + lg) ^ (lr & 7)) * 8));
                acc[df] = __builtin_amdgcn_mfma_f32_16x16x32_bf16(ap, bv, acc[df], 0, 0, 0);
            }
        }
        __syncthreads();
    }
    #pragma unroll
    for (int df = 0; df < 8; ++df)
        #pragma unroll
        for (int r = 0; r < 4; ++r) {
            int qg = qw + lg * 4 + r;
            ab[kqbase + (size_t)qg * DD + df * 16 + lr] = (bf16_t)(acc[df][r] / lrun[r]);
        }
}

extern "C" void kernel_launch(void* const* d_in, const int* in_sizes, int n_in,
                              void* d_out, int out_size, void* d_ws, size_t ws_size,
                              hipStream_t stream) {
    const float* hs  = (const float*)d_in[0];
    // d_in[1] = attention_mask (exactly causal) — applied analytically
    const float* Wq  = (const float*)d_in[2];
    const float* Wk  = (const float*)d_in[3];
    const float* Wv  = (const float*)d_in[4];
    const float* Wo  = (const float*)d_in[5];
    const float* Wg  = (const float*)d_in[6];
    const float* Wu  = (const float*)d_in[7];
    const float* Wd  = (const float*)d_in[8];
    const float* ln1 = (const float*)d_in[9];
    const float* ln2 = (const float*)d_in[10];

    char* ws = (char*)d_ws;
    const size_t MB = 1u << 20;
    bf16_t* xb     = (bf16_t*)(ws);                 // 16 MiB [M][D]
    bf16_t* qb     = (bf16_t*)(ws + 16 * MB);       // 16 MiB
    bf16_t* kb     = (bf16_t*)(ws + 32 * MB);       // 16 MiB
    bf16_t* vtb    = (bf16_t*)(ws + 48 * MB);       // 16 MiB [B][D][S] (written by V-gemm EPI2)
    bf16_t* hidden = (bf16_t*)(ws + 64 * MB);       // 8 MiB bf16 [M][D], written at Wo step
    float*  cosb   = (float*)(ws + 80 * MB);        // 1 MiB
    float*  sinb   = (float*)(ws + 81 * MB);        // 1 MiB
    bf16_t* wtA    = (bf16_t*)(ws + 96 * MB);       // 23.5 MiB transposed-weight scratch A
    bf16_t* wtB    = (bf16_t*)d_out;                // d_out (32 MiB) as scratch B until final gemm
    bf16_t* ab = xb;   // attn out reuses xb
    bf16_t* yb = xb;   // ln2 out reuses xb
    bf16_t* gb = qb;   // h = silu(gate)*up [M][I] = 43 MiB, reuses q/k/vtb region

    if (ws_size < (size_t)(98 * MB) + (size_t)II * DD * 2) return;

    // 1. LN1
    rmsnorm_k<<<MM, 256, 0, stream>>>(hs, ln1, xb);
    // 2. RoPE tables
    rope_tables_k<<<SS, 128, 0, stream>>>(cosb, sinb);
    // 3-5. Q & K fused (shared A-tile) — dual-B GEMM
    convT_k<<<dim3(DD / 64, DD / 64), 256, 0, stream>>>(Wq, wtA, DD, DD);
    convT_k<<<dim3(DD / 64, DD / 64), 256, 0, stream>>>(Wk, wtB, DD, DD);
    gemm_dual<0><<<dim3(DD / 128, MM / 128), 256, 0, stream>>>(xb, wtA, wtB, qb, kb, MM, DD, DD);
    // 6-7. V projection — writes vtb directly transposed (EPI 2)
    convT_k<<<dim3(DD / 64, DD / 64), 256, 0, stream>>>(Wv, wtA, DD, DD);
    gemm_bt<2><<<dim3(DD / 128, MM / 128), 256, 0, stream>>>(xb, wtA, vtb, nullptr, MM, DD, DD);
    // 8. RoPE on q,k
    rope_apply_k<<<(MM * HH * 64) / 256, 256, 0, stream>>>(qb, kb, cosb, sinb);
    // 9. attention (v2 + T13)
    attn_k<<<1024, 256, 0, stream>>>(qb, kb, vtb, ab);
    // 10-11. Wo + residual -> hidden (bf16)
    convT_k<<<dim3(DD / 64, DD / 64), 256, 0, stream>>>(Wo, wtA, DD, DD);
    gemm_bt<1><<<dim3(DD / 128, MM / 128), 256, 0, stream>>>(ab, wtA, hidden, hs, MM, DD, DD);
    // 12. LN2 (bf16 input)
    rmsnorm_b<<<MM, 256, 0, stream>>>(hidden, ln2, yb);
    // 13-15. gate & up fused (shared A-tile) + silu-mul epilogue -> gb
    convT_k<<<dim3(II / 64, DD / 64), 256, 0, stream>>>(Wg, wtA, DD, II);
    convT_k<<<dim3(II / 64, DD / 64), 256, 0, stream>>>(Wu, wtB, DD, II);
    gemm_dual<1><<<dim3(II / 128, MM / 128), 256, 0, stream>>>(yb, wtA, wtB, gb, nullptr, MM, II, DD);
    // 16-17. out = hidden + h @ Wd (f32 out, bf16 res)
    convT_k<<<dim3(DD / 64, II / 64), 256, 0, stream>>>(Wd, wtA, II, DD);
    gemm_bt<3><<<dim3(DD / 128, MM / 128), 256, 0, stream>>>(gb, wtA, (float*)d_out, hidden, MM, DD, II);
}

// Round 18
// 586.652 us; speedup vs baseline: 1.1458x; 1.0221x over previous
//
#include <hip/hip_runtime.h>
#include <hip/hip_bf16.h>
#include <cmath>

typedef __bf16 bf16_t;
typedef __bf16 bf16x8 __attribute__((ext_vector_type(8)));
typedef float f32x4 __attribute__((ext_vector_type(4)));
typedef unsigned short ushort8 __attribute__((ext_vector_type(8)));

#define DEV __device__ __forceinline__

static constexpr int BB = 2, SS = 2048, DD = 2048, HH = 16, HDIM = 128, II = 5504;
static constexpr int MM = BB * SS; // 4096

DEV void gload_lds16(const void* g, void* l) {
    __builtin_amdgcn_global_load_lds(
        (__attribute__((address_space(1))) void*)const_cast<void*>(g),
        (__attribute__((address_space(3))) void*)l, 16, 0, 0);
}

// ---------------- RMSNorm: f32 in -> bf16 out ----------------
__global__ __launch_bounds__(256) void rmsnorm_k(const float* __restrict__ x,
                                                 const float* __restrict__ w,
                                                 bf16_t* __restrict__ out) {
    int row = blockIdx.x;
    int t = threadIdx.x;
    const float4* xr = (const float4*)(x + (size_t)row * DD);
    float4 a = xr[t];
    float4 b = xr[t + 256];
    float ss = a.x * a.x + a.y * a.y + a.z * a.z + a.w * a.w +
               b.x * b.x + b.y * b.y + b.z * b.z + b.w * b.w;
    for (int m = 1; m < 64; m <<= 1) ss += __shfl_xor(ss, m);
    __shared__ float red[4];
    int lane = t & 63, wv = t >> 6;
    if (lane == 0) red[wv] = ss;
    __syncthreads();
    float scale = rsqrtf((red[0] + red[1] + red[2] + red[3]) * (1.0f / DD) + 1e-6f);
    const float4* w4 = (const float4*)w;
    float4 wa = w4[t], wb = w4[t + 256];
    bf16_t* o = out + (size_t)row * DD;
    union { bf16_t h[4]; ushort4 u; } pa, pb;
    pa.h[0] = (bf16_t)(a.x * scale * wa.x); pa.h[1] = (bf16_t)(a.y * scale * wa.y);
    pa.h[2] = (bf16_t)(a.z * scale * wa.z); pa.h[3] = (bf16_t)(a.w * scale * wa.w);
    pb.h[0] = (bf16_t)(b.x * scale * wb.x); pb.h[1] = (bf16_t)(b.y * scale * wb.y);
    pb.h[2] = (bf16_t)(b.z * scale * wb.z); pb.h[3] = (bf16_t)(b.w * scale * wb.w);
    ((ushort4*)o)[t] = pa.u;
    ((ushort4*)o)[t + 256] = pb.u;
}

// ---------------- RMSNorm: bf16 in -> bf16 out ----------------
__global__ __launch_bounds__(256) void rmsnorm_b(const bf16_t* __restrict__ x,
                                                 const float* __restrict__ w,
                                                 bf16_t* __restrict__ out) {
    int row = blockIdx.x;
    int t = threadIdx.x;
    bf16x8 v = *(const bf16x8*)(x + (size_t)row * DD + t * 8);
    float f[8];
    float ss = 0.f;
    #pragma unroll
    for (int j = 0; j < 8; ++j) { f[j] = (float)v[j]; ss += f[j] * f[j]; }
    for (int m = 1; m < 64; m <<= 1) ss += __shfl_xor(ss, m);
    __shared__ float red[4];
    int lane = t & 63, wv = t >> 6;
    if (lane == 0) red[wv] = ss;
    __syncthreads();
    float scale = rsqrtf((red[0] + red[1] + red[2] + red[3]) * (1.0f / DD) + 1e-6f);
    const float4* w4 = (const float4*)w;
    float4 wa = w4[t * 2], wb = w4[t * 2 + 1];
    bf16x8 o;
    o[0] = (bf16_t)(f[0] * scale * wa.x); o[1] = (bf16_t)(f[1] * scale * wa.y);
    o[2] = (bf16_t)(f[2] * scale * wa.z); o[3] = (bf16_t)(f[3] * scale * wa.w);
    o[4] = (bf16_t)(f[4] * scale * wb.x); o[5] = (bf16_t)(f[5] * scale * wb.y);
    o[6] = (bf16_t)(f[6] * scale * wb.z); o[7] = (bf16_t)(f[7] * scale * wb.w);
    *(bf16x8*)(out + (size_t)row * DD + t * 8) = o;
}

// ---------------- RoPE tables (compact [S][64]) ----------------
__global__ void rope_tables_k(float* __restrict__ cosb, float* __restrict__ sinb) {
    int s = blockIdx.x;
    int j = threadIdx.x;       // 0..63
    float inv = powf(10000.0f, -(2.0f * (float)j) / 128.0f);
    float ang = (float)s * inv;
    cosb[s * 64 + j] = cosf(ang);
    sinb[s * 64 + j] = sinf(ang);
}

// ---------------- convT v2: W[K][N] f32 -> Wt[N][K] bf16, 64x64 tile, vectorized ----------------
__global__ __launch_bounds__(256) void convT_k(const float* __restrict__ W,
                                               bf16_t* __restrict__ Wt,
                                               int K, int N) {
    __shared__ float tile[64][65];
    int n0 = blockIdx.x * 64, k0 = blockIdx.y * 64;
    int t = threadIdx.x;
    int r = t >> 4, cq = t & 15;
    #pragma unroll
    for (int it = 0; it < 4; ++it) {
        int row = it * 16 + r;
        float4 v = *(const float4*)(W + (size_t)(k0 + row) * N + n0 + cq * 4);
        tile[row][cq * 4 + 0] = v.x;
        tile[row][cq * 4 + 1] = v.y;
        tile[row][cq * 4 + 2] = v.z;
        tile[row][cq * 4 + 3] = v.w;
    }
    __syncthreads();
    int n = t >> 2, kq = t & 3;
    #pragma unroll
    for (int it = 0; it < 2; ++it) {
        int k = (it * 4 + kq) * 8;
        union { bf16_t h[8]; ushort8 u; } p;
        #pragma unroll
        for (int j = 0; j < 8; ++j) p.h[j] = (bf16_t)tile[k + j][n];
        *(ushort8*)(Wt + (size_t)(n0 + n) * K + k0 + k) = p.u;
    }
}

// ---------------- GEMM (r5-proven): C = A[M][K] * Bt[N][K]^T ----------------
// EPI 0: bf16 store. EPI 1: bf16 store = f32res + acc (Wo+residual).
// EPI 2: V transposed store -> vtb[b][n][s]. EPI 3: f32 store = bf16res + acc (down+residual).
template <int EPI>
__global__ __launch_bounds__(256, 2) void gemm_bt(const bf16_t* __restrict__ A,
                                                  const bf16_t* __restrict__ Bt,
                                                  void* __restrict__ outp,
                                                  const void* __restrict__ res,
                                                  int M, int N, int K) {
    __shared__ __align__(16) bf16_t ldsA[128 * 64];
    __shared__ __align__(16) bf16_t ldsB[128 * 64];
    int tid = threadIdx.x, lane = tid & 63, w = tid >> 6;
    int lr = lane & 15, lg = lane >> 4;

    int GX = gridDim.x, GYd = gridDim.y;
    int bid = blockIdx.y * GX + blockIdx.x;
    int nwg = GX * GYd;
    int qc = nwg >> 3, rc = nwg & 7;
    int xcd = bid & 7, jj = bid >> 3;
    int wg = (xcd < rc ? xcd * (qc + 1) : rc * (qc + 1) + (xcd - rc) * qc) + jj;
    int bx = wg / GYd;
    int by = wg % GYd;

    int m0 = by * 128, n0 = bx * 128;
    int wr = w >> 1, wc = w & 1;
    f32x4 acc[4][4] = {};
    int srow = w * 8 + (lane >> 3);  // 0..31
    int sslot = lane & 7;

    for (int kt = 0; kt < K; kt += 64) {
        for (int i = 0; i < 4; ++i) {
            int row = i * 32 + srow;
            int sp = sslot ^ (row & 7);
            gload_lds16(A + (size_t)(m0 + row) * K + kt + sp * 8,
                        ldsA + i * 2048 + w * 512);
            gload_lds16(Bt + (size_t)(n0 + row) * K + kt + sp * 8,
                        ldsB + i * 2048 + w * 512);
        }
        asm volatile("s_waitcnt vmcnt(0)" ::: "memory");
        __syncthreads();
        for (int kk = 0; kk < 2; ++kk) {
            bf16x8 af[4], bfm[4];
            for (int x = 0; x < 4; ++x) {
                int ra = wr * 64 + x * 16 + lr;
                int sa = (kk * 4 + lg) ^ (ra & 7);
                af[x] = *(const bf16x8*)(ldsA + ra * 64 + sa * 8);
                int rb = wc * 64 + x * 16 + lr;
                int sb = (kk * 4 + lg) ^ (rb & 7);
                bfm[x] = *(const bf16x8*)(ldsB + rb * 64 + sb * 8);
            }
            for (int mi = 0; mi < 4; ++mi)
                for (int ni = 0; ni < 4; ++ni)
                    acc[mi][ni] = __builtin_amdgcn_mfma_f32_16x16x32_bf16(
                        af[mi], bfm[ni], acc[mi][ni], 0, 0, 0);
        }
        __syncthreads();
    }

    for (int mi = 0; mi < 4; ++mi) {
        int mbase = m0 + wr * 64 + mi * 16 + lg * 4;
        for (int ni = 0; ni < 4; ++ni) {
            int n = n0 + wc * 64 + ni * 16 + lr;
            f32x4 v = acc[mi][ni];
            if (EPI == 2) {
                int b = mbase >> 11;
                int srw = mbase & (SS - 1);
                union { bf16_t h[4]; ushort4 u; } p;
                p.h[0] = (bf16_t)v[0]; p.h[1] = (bf16_t)v[1];
                p.h[2] = (bf16_t)v[2]; p.h[3] = (bf16_t)v[3];
                *(ushort4*)((bf16_t*)outp + (size_t)b * DD * SS + (size_t)n * SS + srw) = p.u;
            } else {
                for (int r = 0; r < 4; ++r) {
                    size_t idx = (size_t)(mbase + r) * N + n;
                    if (EPI == 0) {
                        ((bf16_t*)outp)[idx] = (bf16_t)v[r];
                    } else if (EPI == 1) {
                        ((bf16_t*)outp)[idx] = (bf16_t)(((const float*)res)[idx] + v[r]);
                    } else {
                        ((float*)outp)[idx] = (float)((const bf16_t*)res)[idx] + v[r];
                    }
                }
            }
        }
    }
}

// ---------------- Dual-B GEMM with fragment-pair column remap ----------------
// d(ni) = wc*32 + (ni&1)*16 + (ni>>1)*64 + lr  -> fragments ni and ni+2 of the SAME
// thread hold the RoPE pair (d, d+64).
// EPI 0 (QK): RoPE applied in epilogue (one cos/sin per pair), bf16 stores.
// EPI 1 (gate/up): out1 = bf16( silu(acc1) * acc2 ), remapped cols.
template <int EPI>
__global__ __launch_bounds__(256, 2) void gemm_dual(const bf16_t* __restrict__ A,
                                                    const bf16_t* __restrict__ B1,
                                                    const bf16_t* __restrict__ B2,
                                                    bf16_t* __restrict__ out1,
                                                    bf16_t* __restrict__ out2,
                                                    const float* __restrict__ cosb,
                                                    const float* __restrict__ sinb,
                                                    int M, int N, int K) {
    __shared__ __align__(16) bf16_t ldsA[128 * 64];
    __shared__ __align__(16) bf16_t ldsB1[128 * 64];
    __shared__ __align__(16) bf16_t ldsB2[128 * 64];
    int tid = threadIdx.x, lane = tid & 63, w = tid >> 6;
    int lr = lane & 15, lg = lane >> 4;

    int GX = gridDim.x, GYd = gridDim.y;
    int bid = blockIdx.y * GX + blockIdx.x;
    int nwg = GX * GYd;
    int qc = nwg >> 3, rc = nwg & 7;
    int xcd = bid & 7, jj = bid >> 3;
    int wg = (xcd < rc ? xcd * (qc + 1) : rc * (qc + 1) + (xcd - rc) * qc) + jj;
    int bx = wg / GYd;
    int by = wg % GYd;

    int m0 = by * 128, n0 = bx * 128;
    int wr = w >> 1, wc = w & 1;
    f32x4 acc1[4][4] = {};
    f32x4 acc2[4][4] = {};
    int srow = w * 8 + (lane >> 3);  // 0..31
    int sslot = lane & 7;

    for (int kt = 0; kt < K; kt += 64) {
        for (int i = 0; i < 4; ++i) {
            int row = i * 32 + srow;
            int sp = sslot ^ (row & 7);
            gload_lds16(A  + (size_t)(m0 + row) * K + kt + sp * 8, ldsA  + i * 2048 + w * 512);
            gload_lds16(B1 + (size_t)(n0 + row) * K + kt + sp * 8, ldsB1 + i * 2048 + w * 512);
            gload_lds16(B2 + (size_t)(n0 + row) * K + kt + sp * 8, ldsB2 + i * 2048 + w * 512);
        }
        asm volatile("s_waitcnt vmcnt(0)" ::: "memory");
        __syncthreads();
        for (int kk = 0; kk < 2; ++kk) {
            bf16x8 af[4], bfm[4];
            for (int x = 0; x < 4; ++x) {
                int ra = wr * 64 + x * 16 + lr;
                af[x] = *(const bf16x8*)(ldsA + ra * 64 + (((kk * 4 + lg) ^ (ra & 7)) * 8));
            }
            for (int x = 0; x < 4; ++x) {
                int rb = wc * 32 + (x & 1) * 16 + (x >> 1) * 64 + lr;   // remapped
                bfm[x] = *(const bf16x8*)(ldsB1 + rb * 64 + (((kk * 4 + lg) ^ (rb & 7)) * 8));
            }
            for (int mi = 0; mi < 4; ++mi)
                for (int ni = 0; ni < 4; ++ni)
                    acc1[mi][ni] = __builtin_amdgcn_mfma_f32_16x16x32_bf16(
                        af[mi], bfm[ni], acc1[mi][ni], 0, 0, 0);
            for (int x = 0; x < 4; ++x) {
                int rb = wc * 32 + (x & 1) * 16 + (x >> 1) * 64 + lr;   // remapped
                bfm[x] = *(const bf16x8*)(ldsB2 + rb * 64 + (((kk * 4 + lg) ^ (rb & 7)) * 8));
            }
            for (int mi = 0; mi < 4; ++mi)
                for (int ni = 0; ni < 4; ++ni)
                    acc2[mi][ni] = __builtin_amdgcn_mfma_f32_16x16x32_bf16(
                        af[mi], bfm[ni], acc2[mi][ni], 0, 0, 0);
        }
        __syncthreads();
    }

    for (int mi = 0; mi < 4; ++mi) {
        int mbase = m0 + wr * 64 + mi * 16 + lg * 4;
        if (EPI == 0) {
            // RoPE-fused q/k store: pairs (ni, ni+2) = (d, d+64), one cos/sin per pair
            #pragma unroll
            for (int ni = 0; ni < 2; ++ni) {
                int j = wc * 32 + ni * 16 + lr;          // 0..63
                size_t nlo = n0 + j, nhi = nlo + 64;
                f32x4 qlo = acc1[mi][ni], qhi = acc1[mi][ni + 2];
                f32x4 klo = acc2[mi][ni], khi = acc2[mi][ni + 2];
                #pragma unroll
                for (int r = 0; r < 4; ++r) {
                    int m = mbase + r;
                    int s = m & (SS - 1);
                    float c  = cosb[s * 64 + j];
                    float sn = sinb[s * 64 + j];
                    size_t ilo = (size_t)m * N + nlo;
                    size_t ihi = (size_t)m * N + nhi;
                    out1[ilo] = (bf16_t)(qlo[r] * c - qhi[r] * sn);
                    out1[ihi] = (bf16_t)(qhi[r] * c + qlo[r] * sn);
                    out2[ilo] = (bf16_t)(klo[r] * c - khi[r] * sn);
                    out2[ihi] = (bf16_t)(khi[r] * c + klo[r] * sn);
                }
            }
        } else {
            for (int ni = 0; ni < 4; ++ni) {
                int n = n0 + wc * 32 + (ni & 1) * 16 + (ni >> 1) * 64 + lr;
                f32x4 v1 = acc1[mi][ni];
                f32x4 v2 = acc2[mi][ni];
                for (int r = 0; r < 4; ++r) {
                    size_t idx = (size_t)(mbase + r) * N + n;
                    float g = v1[r];
                    float sg = g / (1.0f + __expf(-g));
                    out1[idx] = (bf16_t)(sg * v2[r]);
                }
            }
        }
    }
}

// ---------------- Flash attention v2 + T13 defer-max (causal), KVBLK=64 ----------------
__global__ __launch_bounds__(256, 3) void attn_k(const bf16_t* __restrict__ qb,
                                                 const bf16_t* __restrict__ kb,
                                                 const bf16_t* __restrict__ vtb,
                                                 bf16_t* __restrict__ ab) {
    __shared__ __align__(16) bf16_t ldsK[64 * 128];   // [k][d], 16B slots src-swizzled
    __shared__ __align__(16) bf16_t ldsVt[128 * 64];  // [d][k], 16B slots src-swizzled
    __shared__ __align__(16) float pbuf[4][16][68];   // per wave: [q][k 0..63] 4-col swizzled
    int bid = blockIdx.x;
    int band = 31 - (bid >> 5);      // heavy bands dispatched first
    int bh = bid & 31;
    int b = bh >> 4, h = bh & 15;
    int q0 = band * 64;
    int tid = threadIdx.x, lane = tid & 63, w = tid >> 6;
    int lr = lane & 15, lg = lane >> 4;
    size_t kqbase = ((size_t)b * SS) * DD + h * HDIM;
    size_t vtbase = ((size_t)(b * HH + h)) * HDIM * SS;
    int qw = q0 + w * 16;

    bf16x8 aq[4];
    #pragma unroll
    for (int kd = 0; kd < 4; ++kd)
        aq[kd] = *(const bf16x8*)(qb + kqbase + (size_t)(qw + lr) * DD + kd * 32 + lg * 8);

    f32x4 acc[8] = {};
    float mrun[4], lrun[4];
    #pragma unroll
    for (int r = 0; r < 4; ++r) { mrun[r] = -1e30f; lrun[r] = 0.f; }
    const float scale = 0.08838834764831845f;  // 1/sqrt(128)

    for (int t = 0; t <= band; ++t) {
        int kk0 = t * 64;
        #pragma unroll
        for (int it = 0; it < 4; ++it) {
            int cid = it * 256 + tid;
            int kr = cid >> 4, kslot = cid & 15;
            gload_lds16(kb + kqbase + (size_t)(kk0 + kr) * DD + ((kslot ^ (kr & 7)) * 8),
                        ldsK + it * 2048 + w * 512);
            int vd = cid >> 3, vslot = cid & 7;
            gload_lds16(vtb + vtbase + (size_t)vd * SS + kk0 + ((vslot ^ (vd & 7)) * 8),
                        ldsVt + it * 2048 + w * 512);
        }
        asm volatile("s_waitcnt vmcnt(0)" ::: "memory");
        __syncthreads();

        // QK^T: S[q 16][k 64]
        f32x4 sf[4];
        #pragma unroll
        for (int nf = 0; nf < 4; ++nf) {
            f32x4 d = {};
            int row = nf * 16 + lr;
            #pragma unroll
            for (int kd = 0; kd < 4; ++kd) {
                bf16x8 bk = *(const bf16x8*)(ldsK + row * 128 +
                                             (((kd * 4 + lg) ^ (lr & 7)) * 8));
                d = __builtin_amdgcn_mfma_f32_16x16x32_bf16(aq[kd], bk, d, 0, 0, 0);
            }
            sf[nf] = d;
        }
        // per-row masked max
        float mx[4], dmax = -1e30f;
        #pragma unroll
        for (int r = 0; r < 4; ++r) {
            int qg = qw + lg * 4 + r;
            float m2 = -1e30f;
            #pragma unroll
            for (int nf = 0; nf < 4; ++nf) {
                float sv = sf[nf][r] * scale;
                if (kk0 + nf * 16 + lr > qg) sv = -1e30f;
                m2 = fmaxf(m2, sv);
            }
            m2 = fmaxf(m2, __shfl_xor(m2, 1));
            m2 = fmaxf(m2, __shfl_xor(m2, 2));
            m2 = fmaxf(m2, __shfl_xor(m2, 4));
            m2 = fmaxf(m2, __shfl_xor(m2, 8));
            mx[r] = m2;
            dmax = fmaxf(dmax, m2 - mrun[r]);
        }
        // T13: O-rescale only when some row's max grew past the threshold (rare)
        if (!__all(dmax <= 8.0f)) {
            #pragma unroll
            for (int r = 0; r < 4; ++r) {
                float mnew = fmaxf(mrun[r], mx[r]);
                float corr = __expf(mrun[r] - mnew);
                lrun[r] *= corr;
                mrun[r] = mnew;
                #pragma unroll
                for (int df = 0; df < 8; ++df) acc[df][r] *= corr;
            }
        }
        #pragma unroll
        for (int r = 0; r < 4; ++r) {
            int qg = qw + lg * 4 + r;
            float rs = 0.f;
            #pragma unroll
            for (int nf = 0; nf < 4; ++nf) {
                float sv = sf[nf][r] * scale;
                if (kk0 + nf * 16 + lr > qg) sv = -1e30f;
                float p = __expf(sv - mrun[r]);
                rs += p;
                pbuf[w][lg * 4 + r][nf * 16 + (lr ^ (r << 2))] = p;
            }
            rs += __shfl_xor(rs, 1); rs += __shfl_xor(rs, 2);
            rs += __shfl_xor(rs, 4); rs += __shfl_xor(rs, 8);
            lrun[r] += rs;
        }
        asm volatile("s_waitcnt lgkmcnt(0)" ::: "memory");
        // PV: two K=32 steps; A-frag rebuilt from pbuf (wave-local)
        #pragma unroll
        for (int ks2 = 0; ks2 < 2; ++ks2) {
            int nfA = ks2 * 2 + (lg >> 1);
            int off = (lg & 1) * 8;
            int sw = (lr & 3) << 2;
            float4 a0 = *(const float4*)&pbuf[w][lr][nfA * 16 + (off ^ sw)];
            float4 a1 = *(const float4*)&pbuf[w][lr][nfA * 16 + ((off + 4) ^ sw)];
            bf16x8 ap;
            ap[0] = (bf16_t)a0.x; ap[1] = (bf16_t)a0.y;
            ap[2] = (bf16_t)a0.z; ap[3] = (bf16_t)a0.w;
            ap[4] = (bf16_t)a1.x; ap[5] = (bf16_t)a1.y;
            ap[6] = (bf16_t)a1.z; ap[7] = (bf16_t)a1.w;
            #pragma unroll
            for (int df = 0; df < 8; ++df) {
                bf16x8 bv = *(const bf16x8*)(ldsVt + (df * 16 + lr) * 64 +
                                             (((ks2 * 4 + lg) ^ (lr & 7)) * 8));
                acc[df] = __builtin_amdgcn_mfma_f32_16x16x32_bf16(ap, bv, acc[df], 0, 0, 0);
            }
        }
        __syncthreads();
    }
    #pragma unroll
    for (int df = 0; df < 8; ++df)
        #pragma unroll
        for (int r = 0; r < 4; ++r) {
            int qg = qw + lg * 4 + r;
            ab[kqbase + (size_t)qg * DD + df * 16 + lr] = (bf16_t)(acc[df][r] / lrun[r]);
        }
}

extern "C" void kernel_launch(void* const* d_in, const int* in_sizes, int n_in,
                              void* d_out, int out_size, void* d_ws, size_t ws_size,
                              hipStream_t stream) {
    const float* hs  = (const float*)d_in[0];
    // d_in[1] = attention_mask (exactly causal) — applied analytically
    const float* Wq  = (const float*)d_in[2];
    const float* Wk  = (const float*)d_in[3];
    const float* Wv  = (const float*)d_in[4];
    const float* Wo  = (const float*)d_in[5];
    const float* Wg  = (const float*)d_in[6];
    const float* Wu  = (const float*)d_in[7];
    const float* Wd  = (const float*)d_in[8];
    const float* ln1 = (const float*)d_in[9];
    const float* ln2 = (const float*)d_in[10];

    char* ws = (char*)d_ws;
    const size_t MB = 1u << 20;
    bf16_t* xb     = (bf16_t*)(ws);                 // 16 MiB [M][D]
    bf16_t* qb     = (bf16_t*)(ws + 16 * MB);       // 16 MiB
    bf16_t* kb     = (bf16_t*)(ws + 32 * MB);       // 16 MiB
    bf16_t* vtb    = (bf16_t*)(ws + 48 * MB);       // 16 MiB [B][D][S] (written by V-gemm EPI2)
    bf16_t* hidden = (bf16_t*)(ws + 64 * MB);       // 8 MiB bf16 [M][D], written at Wo step
    float*  cosb   = (float*)(ws + 80 * MB);        // 0.5 MiB [S][64]
    float*  sinb   = (float*)(ws + 81 * MB);        // 0.5 MiB
    bf16_t* wtA    = (bf16_t*)(ws + 96 * MB);       // 23.5 MiB transposed-weight scratch A
    bf16_t* wtB    = (bf16_t*)d_out;                // d_out (32 MiB) as scratch B until final gemm
    bf16_t* ab = xb;   // attn out reuses xb
    bf16_t* yb = xb;   // ln2 out reuses xb
    bf16_t* gb = qb;   // h = silu(gate)*up [M][I] = 43 MiB, reuses q/k/vtb region

    if (ws_size < (size_t)(98 * MB) + (size_t)II * DD * 2) return;

    // 1. LN1
    rmsnorm_k<<<MM, 256, 0, stream>>>(hs, ln1, xb);
    // 2. RoPE tables (compact [S][64])
    rope_tables_k<<<SS, 64, 0, stream>>>(cosb, sinb);
    // 3-5. Q & K fused (shared A-tile) — dual-B GEMM with fused RoPE epilogue
    convT_k<<<dim3(DD / 64, DD / 64), 256, 0, stream>>>(Wq, wtA, DD, DD);
    convT_k<<<dim3(DD / 64, DD / 64), 256, 0, stream>>>(Wk, wtB, DD, DD);
    gemm_dual<0><<<dim3(DD / 128, MM / 128), 256, 0, stream>>>(xb, wtA, wtB, qb, kb, cosb, sinb, MM, DD, DD);
    // 6-7. V projection — writes vtb directly transposed (EPI 2)
    convT_k<<<dim3(DD / 64, DD / 64), 256, 0, stream>>>(Wv, wtA, DD, DD);
    gemm_bt<2><<<dim3(DD / 128, MM / 128), 256, 0, stream>>>(xb, wtA, vtb, nullptr, MM, DD, DD);
    // 8. attention (v2 + T13)
    attn_k<<<1024, 256, 0, stream>>>(qb, kb, vtb, ab);
    // 9-10. Wo + residual -> hidden (bf16)
    convT_k<<<dim3(DD / 64, DD / 64), 256, 0, stream>>>(Wo, wtA, DD, DD);
    gemm_bt<1><<<dim3(DD / 128, MM / 128), 256, 0, stream>>>(ab, wtA, hidden, hs, MM, DD, DD);
    // 11. LN2 (bf16 input)
    rmsnorm_b<<<MM, 256, 0, stream>>>(hidden, ln2, yb);
    // 12-14. gate & up fused (shared A-tile) + silu-mul epilogue -> gb
    convT_k<<<dim3(II / 64, DD / 64), 256, 0, stream>>>(Wg, wtA, DD, II);
    convT_k<<<dim3(II / 64, DD / 64), 256, 0, stream>>>(Wu, wtB, DD, II);
    gemm_dual<1><<<dim3(II / 128, MM / 128), 256, 0, stream>>>(yb, wtA, wtB, gb, nullptr, nullptr, nullptr, MM, II, DD);
    // 15-16. out = hidden + h @ Wd (f32 out, bf16 res)
    convT_k<<<dim3(DD / 64, II / 64), 256, 0, stream>>>(Wd, wtA, II, DD);
    gemm_bt<3><<<dim3(DD / 128, MM / 128), 256, 0, stream>>>(gb, wtA, (float*)d_out, hidden, MM, DD, II);
}